// Round 1
// baseline (871.460 us; speedup 1.0000x reference)
//
#include <hip/hip_runtime.h>

#define BSZ 4
#define XD 1024
#define HD 256
#define LL 4
#define VTD 4096
#define WDIM 64
#define RDIM 8
#define ND 4096
#define ETD 747
#define IND 2048
#define EPSF 1e-8f

// ---- workspace layout (float offsets) ----
#define OFF_PRE 0            // [L][4][BS][H] = 16384   (atomic, zeroed)
#define OFF_IV 16384         // [BS][747]    = 2988    (atomic, zeroed)
#define OFF_SP 19372         // [BS][8]                 (atomic, zeroed)
#define OFF_SW 19404         // [BS][8]                 (atomic, zeroed)
#define OFF_RV 19436         // [BS][64][8] = 2048      (atomic, zeroed)
#define ZERO_FLOATS 21484
#define OFF_FLAT 21484       // [BS][1024]
#define OFF_WKN 25580        // [BS][64]
#define OFF_RKN 25836        // [BS][8][64]
#define OFF_RB 27884         // [BS][8]
#define OFF_WB 27916         // [BS]
#define OFF_ER 27920         // [BS][64]
#define OFF_WV 28176         // [BS][64]
#define OFF_FR 28432         // [BS][8]
#define OFF_AG 28464         // [BS]
#define OFF_WG 28468         // [BS]
#define OFF_MD 28472         // [BS][8][3]
#define OFF_U 28568          // [BS][N]
#define OFF_AW 44952         // [BS][N]
#define OFF_CW 61336         // [BS][N]
#define OFF_WW 77720         // [BS][N]
#define OFF_WRW 94104        // [BS][N][8]
#define OFF_NM 225176        // [BS][N][64]
#define OFF_FWD 1273752      // [BS][N][8]
#define OFF_BWD 1404824      // [BS][N][8]
#define OFF_RCS 1535896      // [BS][N][8]

__device__ __forceinline__ float sigf(float x){ return 1.f/(1.f+expf(-x)); }
__device__ __forceinline__ float splus(float z){ return fmaxf(z,0.f) + log1pf(expf(-fabsf(z))); }

// ---------- LSTM: known-input part of all gates, all layers ----------
__global__ void k_pre(const float* __restrict__ x_in, const float* __restrict__ lrv,
                      const float* __restrict__ ch,
                      const float* __restrict__ Wi, const float* __restrict__ Wf,
                      const float* __restrict__ Wo, const float* __restrict__ Wsg,
                      float* __restrict__ pre){
  int kc = blockIdx.x;          // 0..6 (7 chunks of 256 over k<1792)
  int lg = blockIdx.y;          // 0..15
  int l = lg >> 2, g = lg & 3;
  int t = threadIdx.x;
  __shared__ float s[4][256];
  for (int idx = t; idx < 1024; idx += 256){
    int b = idx >> 8, kk = idx & 255;
    int k = kc*256 + kk;
    float v;
    if (k < 1024)      v = x_in[b*XD + k];
    else if (k < 1536) v = lrv[b*512 + (k-1024)];
    else               v = ch[(b*LL + l)*HD + (k-1536)];
    s[b][kk] = v;
  }
  __syncthreads();
  const float* Wg = (g==0?Wi:g==1?Wf:g==2?Wo:Wsg) + (size_t)l*IND*HD;
  float a0=0,a1=0,a2=0,a3=0;
  for (int kk=0; kk<256; kk++){
    float w = Wg[(size_t)(kc*256+kk)*HD + t];
    a0 += s[0][kk]*w; a1 += s[1][kk]*w; a2 += s[2][kk]*w; a3 += s[3][kk]*w;
  }
  float* p = pre + (size_t)((l*4+g)*4)*HD + t;
  atomicAdd(p + 0*HD, a0); atomicAdd(p + 1*HD, a1);
  atomicAdd(p + 2*HD, a2); atomicAdd(p + 3*HD, a3);
}

// ---------- LSTM: prev-hidden contribution for layer l>0 ----------
__global__ void k_gprev(const float* __restrict__ flat,
                        const float* __restrict__ Wi, const float* __restrict__ Wf,
                        const float* __restrict__ Wo, const float* __restrict__ Wsg,
                        float* __restrict__ pre, int l){
  int kc = blockIdx.x;          // 0..1 (128 k each)
  int g  = blockIdx.y;          // 0..3
  int t = threadIdx.x;
  __shared__ float s[4][128];
  for (int idx = t; idx < 512; idx += 256){
    int b = idx >> 7, kk = idx & 127;
    s[b][kk] = flat[b*1024 + (l-1)*HD + kc*128 + kk];
  }
  __syncthreads();
  const float* Wg = (g==0?Wi:g==1?Wf:g==2?Wo:Wsg) + (size_t)l*IND*HD;
  float a0=0,a1=0,a2=0,a3=0;
  for (int kk=0; kk<128; kk++){
    float w = Wg[(size_t)(1792 + kc*128 + kk)*HD + t];
    a0 += s[0][kk]*w; a1 += s[1][kk]*w; a2 += s[2][kk]*w; a3 += s[3][kk]*w;
  }
  float* p = pre + (size_t)((l*4+g)*4)*HD + t;
  atomicAdd(p + 0*HD, a0); atomicAdd(p + 1*HD, a1);
  atomicAdd(p + 2*HD, a2); atomicAdd(p + 3*HD, a3);
}

// ---------- LSTM: nonlinearity + h write for layer l ----------
__global__ void k_hout(const float* __restrict__ pre,
                       const float* __restrict__ b_i, const float* __restrict__ b_f,
                       const float* __restrict__ b_o, const float* __restrict__ b_s,
                       const float* __restrict__ cc, float* __restrict__ flat, int l){
  int h = threadIdx.x;
  float bi = b_i[l*HD+h], bf = b_f[l*HD+h], bo = b_o[l*HD+h], bs = b_s[l*HD+h];
  for (int b=0;b<BSZ;b++){
    float pi = pre[((l*4+0)*4+b)*HD+h];
    float pf = pre[((l*4+1)*4+b)*HD+h];
    float po = pre[((l*4+2)*4+b)*HD+h];
    float ps = pre[((l*4+3)*4+b)*HD+h];
    float ig = sigf(pi+bi), fg = sigf(pf+bf), og = sigf(po+bo);
    float sg = tanhf(ps+bs);
    float c = fg*cc[(b*LL+l)*HD+h] + ig*sg;
    flat[b*1024 + l*HD + h] = og*tanhf(c);
  }
}

// ---------- y = flat @ W_y (atomic into out) ----------
__global__ void k_wy(const float* __restrict__ flat, const float* __restrict__ W_y,
                     float* __restrict__ out){
  int vc = blockIdx.x, kc = blockIdx.y;   // 16 x 8
  int t = threadIdx.x;
  int v = vc*256 + t;
  __shared__ float s[4][128];
  for (int idx=t; idx<512; idx+=256){ int b=idx>>7, kk=idx&127; s[b][kk]=flat[b*1024 + kc*128+kk]; }
  __syncthreads();
  float a0=0,a1=0,a2=0,a3=0;
  for (int kk=0;kk<128;kk++){
    float w = W_y[(size_t)(kc*128+kk)*VTD + v];
    a0 += s[0][kk]*w; a1 += s[1][kk]*w; a2 += s[2][kk]*w; a3 += s[3][kk]*w;
  }
  atomicAdd(&out[0*VTD+v], a0); atomicAdd(&out[1*VTD+v], a1);
  atomicAdd(&out[2*VTD+v], a2); atomicAdd(&out[3*VTD+v], a3);
}

// ---------- iv = flat @ W_E ----------
__global__ void k_we(const float* __restrict__ flat, const float* __restrict__ W_E,
                     float* __restrict__ iv){
  int vc = blockIdx.x, kc = blockIdx.y;   // 3 x 8
  int t = threadIdx.x;
  int v = vc*256 + t;
  __shared__ float s[4][128];
  for (int idx=t; idx<512; idx+=256){ int b=idx>>7, kk=idx&127; s[b][kk]=flat[b*1024 + kc*128+kk]; }
  __syncthreads();
  if (v >= ETD) return;
  float a0=0,a1=0,a2=0,a3=0;
  for (int kk=0;kk<128;kk++){
    float w = W_E[(size_t)(kc*128+kk)*ETD + v];
    a0 += s[0][kk]*w; a1 += s[1][kk]*w; a2 += s[2][kk]*w; a3 += s[3][kk]*w;
  }
  atomicAdd(&iv[0*ETD+v], a0); atomicAdd(&iv[1*ETD+v], a1);
  atomicAdd(&iv[2*ETD+v], a2); atomicAdd(&iv[3*ETD+v], a3);
}

// ---------- interface vector post-processing ----------
__global__ void k_iface(const float* __restrict__ iv, float* wkn, float* rkn, float* rb,
                        float* wb, float* er, float* wv, float* fr, float* ag, float* wg,
                        float* md){
  int b = blockIdx.x, t = threadIdx.x;
  const float* ivb = iv + b*ETD;
  __shared__ float rk2[8];
  if (t < 8) rk2[t] = 0.f;
  __syncthreads();
  for (int p=0;p<2;p++){
    int idx = t + p*256; int w = idx>>3, r = idx&7;
    float v = ivb[w*8 + r];
    atomicAdd(&rk2[r], v*v);
  }
  float wkv = 0.f, ss = 0.f;
  if (t < 64){ wkv = ivb[520 + t]; ss = wkv*wkv; }
  for (int o=32;o>0;o>>=1) ss += __shfl_xor(ss, o, 64);
  if (t < 64) wkn[b*64 + t] = wkv/(sqrtf(ss)+EPSF);
  __syncthreads();
  for (int p=0;p<2;p++){
    int idx = t + p*256; int w = idx>>3, r = idx&7;
    float v = ivb[w*8 + r];
    rkn[b*512 + r*64 + w] = v/(sqrtf(rk2[r])+EPSF);
  }
  if (t < 8) rb[b*8+t] = 1.f + splus(-ivb[512+t]);
  if (t == 0) wb[b] = 1.f + splus(-ivb[584]);
  if (t < 64){ er[b*64+t] = sigf(ivb[585+t]); wv[b*64+t] = ivb[649+t]; }
  if (t < 8) fr[b*8+t] = sigf(ivb[713+t]);
  if (t == 0) ag[b] = sigf(ivb[721]);
  if (t == 1) wg[b] = sigf(ivb[722]);
  if (t < 8){
    float m0 = ivb[723+t*3], m1 = ivb[723+t*3+1], m2 = ivb[723+t*3+2];
    float mx = fmaxf(m0, fmaxf(m1,m2));
    float e0 = expf(m0-mx), e1 = expf(m1-mx), e2 = expf(m2-mx);
    float inv = 1.f/(e0+e1+e2);
    md[(b*8+t)*3+0]=e0*inv; md[(b*8+t)*3+1]=e1*inv; md[(b*8+t)*3+2]=e2*inv;
  }
}

// ---------- usage u ----------
__global__ void k_psiu(const float* __restrict__ fr, const float* __restrict__ lrw,
                       const float* __restrict__ lus, const float* __restrict__ lww,
                       const float* __restrict__ nf, float* __restrict__ u){
  int gid = blockIdx.x*256 + threadIdx.x;
  int b = gid >> 12, n = gid & 4095;
  size_t bn = (size_t)b*ND + n;
  float psi = 1.f;
  #pragma unroll
  for (int r=0;r<8;r++) psi *= 1.f - fr[b*8+r]*lrw[bn*8+r];
  float a = lus[bn], c = lww[bn];
  u[bn] = (a + c - a*c)*psi*nf[0];
}

// ---------- allocation: bitonic sort + product scan + scatter ----------
__global__ __launch_bounds__(1024) void k_sort(const float* __restrict__ u, float* __restrict__ aw){
  __shared__ float key[4096];
  __shared__ int sidx[4096];
  __shared__ float p[4096];
  int b = blockIdx.x, t = threadIdx.x;
  for (int i=t;i<4096;i+=1024){ key[i]=u[(size_t)b*ND+i]; sidx[i]=i; }
  __syncthreads();
  for (int k=2;k<=4096;k<<=1){
    for (int j=k>>1;j>0;j>>=1){
      for (int i=t;i<4096;i+=1024){
        int ixj = i ^ j;
        if (ixj > i){
          bool asc = ((i & k) == 0);
          float a = key[i], c = key[ixj];
          bool sw = asc ? (a > c) : (a < c);
          if (sw){
            key[i]=c; key[ixj]=a;
            int ti = sidx[i]; sidx[i]=sidx[ixj]; sidx[ixj]=ti;
          }
        }
      }
      __syncthreads();
    }
  }
  for (int i=t;i<4096;i+=1024) p[i]=key[i];
  __syncthreads();
  for (int off=1; off<4096; off<<=1){
    float tv[4];
    #pragma unroll
    for (int q=0;q<4;q++){
      int i = t + q*1024;
      float v = p[i];
      float pv = (i>=off)? p[i-off] : 1.f;
      tv[q] = v*pv;
    }
    __syncthreads();
    #pragma unroll
    for (int q=0;q<4;q++) p[t+q*1024] = tv[q];
    __syncthreads();
  }
  #pragma unroll
  for (int q=0;q<4;q++){
    int i = t + q*1024;
    float cpe = (i>0)? p[i-1] : 1.f;
    aw[(size_t)b*ND + sidx[i]] = (1.f - key[i]) * cpe;
  }
}

// ---------- write content weights (cosine + softmax over N) ----------
__global__ __launch_bounds__(1024) void k_cw(const float* __restrict__ memory,
                                             const float* __restrict__ wkn,
                                             const float* __restrict__ wb,
                                             float* __restrict__ cw){
  int b = blockIdx.x, t = threadIdx.x;
  __shared__ float red[1024];
  __shared__ float wk[64];
  if (t < 64) wk[t] = wkn[b*64+t];
  __syncthreads();
  float wbv = wb[b];
  float s4[4];
  #pragma unroll
  for (int q=0;q<4;q++){
    int n = t + q*1024;
    const float* m = memory + ((size_t)b*ND+n)*64;
    float nr=0.f, d=0.f;
    for (int w=0;w<64;w++){ float mv=m[w]; nr+=mv*mv; d+=mv*wk[w]; }
    s4[q] = wbv * d/(sqrtf(nr)+EPSF);
  }
  float mx = fmaxf(fmaxf(s4[0],s4[1]), fmaxf(s4[2],s4[3]));
  red[t]=mx; __syncthreads();
  for (int s=512;s>0;s>>=1){ if (t<s) red[t]=fmaxf(red[t],red[t+s]); __syncthreads(); }
  float gmx = red[0]; __syncthreads();
  float e4[4], sm=0.f;
  #pragma unroll
  for (int q=0;q<4;q++){ e4[q]=expf(s4[q]-gmx); sm+=e4[q]; }
  red[t]=sm; __syncthreads();
  for (int s=512;s>0;s>>=1){ if (t<s) red[t]+=red[t+s]; __syncthreads(); }
  float inv = 1.f/red[0];
  #pragma unroll
  for (int q=0;q<4;q++) cw[(size_t)b*ND + t + q*1024] = e4[q]*inv;
}

// ---------- ww, wrw, Sp, Sw ----------
__global__ void k_ww(const float* __restrict__ aw, const float* __restrict__ cw,
                     const float* __restrict__ ag, const float* __restrict__ wg,
                     const float* __restrict__ prec, const float* __restrict__ lrw,
                     float* __restrict__ ww, float* __restrict__ wrw,
                     float* __restrict__ Sp, float* __restrict__ Sw){
  int b = blockIdx.y;
  int n = blockIdx.x*256 + threadIdx.x;
  int t = threadIdx.x;
  __shared__ float ssp[8], ssw[8];
  if (t<8){ ssp[t]=0.f; ssw[t]=0.f; }
  __syncthreads();
  size_t bn = (size_t)b*ND + n;
  float agv = ag[b];
  float wv = wg[b]*(agv*aw[bn] + (1.f-agv)*cw[bn]);
  ww[bn] = wv;
  float pv = prec[bn];
  #pragma unroll
  for (int r=0;r<8;r++){
    float rr = lrw[bn*8+r];
    float wr = wv*rr;
    wrw[bn*8+r] = wr;
    atomicAdd(&ssp[r], pv*rr);
    atomicAdd(&ssw[r], wr);
  }
  __syncthreads();
  if (t<8){ atomicAdd(&Sp[b*8+t], ssp[t]); atomicAdd(&Sw[b*8+t], ssw[t]); }
}

// ---------- memory update ----------
__global__ void k_newmem(const float* __restrict__ mem, const float* __restrict__ ww,
                         const float* __restrict__ er, const float* __restrict__ wv,
                         float* __restrict__ nm){
  int gid = blockIdx.x*256 + threadIdx.x;     // 4*4096*64 total
  int b = gid >> 18;
  int rem = gid & 262143;
  int n = rem >> 6, w = rem & 63;
  float wwv = ww[(size_t)b*ND + n];
  nm[gid] = mem[gid]*(1.f - wwv*er[b*64+w]) + wwv*wv[b*64+w];
}

// ---------- forward temporal read weights (row pass over tml) ----------
__global__ __launch_bounds__(256) void k_fw(const float* __restrict__ tml,
    const float* __restrict__ rw, const float* __restrict__ wrw,
    const float* __restrict__ ww, const float* __restrict__ prec,
    const float* __restrict__ Sp, const float* __restrict__ nf_p,
    float* __restrict__ fwv){
  __shared__ float tile[2][32][65];
  __shared__ float rwt[2][64][8];
  __shared__ float wrt[2][64][8];
  __shared__ float sred[256][33];
  int t = threadIdx.x;
  int i0 = blockIdx.x*32;
  int b = blockIdx.y;
  const float* tb = tml + (size_t)b*ND*ND;
  int rg = t & 15, jg = t >> 4;
  int lrow = t >> 4, lc4 = t & 15;      // tile loader
  int ljj = t >> 3, lr = t & 7;         // rw loader
  float A0[8], A1[8], B0[8], B1[8];
  #pragma unroll
  for (int r=0;r<8;r++){A0[r]=0;A1[r]=0;B0[r]=0;B1[r]=0;}
  {
    const float4 v0 = *(const float4*)(tb + (size_t)(i0+lrow)*ND + lc4*4);
    const float4 v1 = *(const float4*)(tb + (size_t)(i0+lrow+16)*ND + lc4*4);
    tile[0][lrow][lc4*4+0]=v0.x; tile[0][lrow][lc4*4+1]=v0.y;
    tile[0][lrow][lc4*4+2]=v0.z; tile[0][lrow][lc4*4+3]=v0.w;
    tile[0][lrow+16][lc4*4+0]=v1.x; tile[0][lrow+16][lc4*4+1]=v1.y;
    tile[0][lrow+16][lc4*4+2]=v1.z; tile[0][lrow+16][lc4*4+3]=v1.w;
    rwt[0][ljj][lr]    = rw[((size_t)b*ND + ljj)*RDIM + lr];
    rwt[0][ljj+32][lr] = rw[((size_t)b*ND + ljj+32)*RDIM + lr];
    wrt[0][ljj][lr]    = wrw[((size_t)b*ND + ljj)*RDIM + lr];
    wrt[0][ljj+32][lr] = wrw[((size_t)b*ND + ljj+32)*RDIM + lr];
  }
  __syncthreads();
  float4 p0, p1; float prw0, prw1, pww0, pww1;
  for (int jt=0; jt<64; jt++){
    int cur = jt & 1;
    if (jt < 63){
      int j0 = (jt+1)*64;
      p0 = *(const float4*)(tb + (size_t)(i0+lrow)*ND + j0 + lc4*4);
      p1 = *(const float4*)(tb + (size_t)(i0+lrow+16)*ND + j0 + lc4*4);
      prw0 = rw[((size_t)b*ND + j0+ljj)*RDIM + lr];
      prw1 = rw[((size_t)b*ND + j0+ljj+32)*RDIM + lr];
      pww0 = wrw[((size_t)b*ND + j0+ljj)*RDIM + lr];
      pww1 = wrw[((size_t)b*ND + j0+ljj+32)*RDIM + lr];
    }
    #pragma unroll
    for (int jj=0;jj<4;jj++){
      int j = jg*4 + jj;
      float t0 = tile[cur][rg][j];
      float t1 = tile[cur][rg+16][j];
      #pragma unroll
      for (int r=0;r<8;r++){
        float rv_ = rwt[cur][j][r];
        float wv_ = wrt[cur][j][r];
        A0[r] += t0*rv_; B0[r] += t0*wv_;
        A1[r] += t1*rv_; B1[r] += t1*wv_;
      }
    }
    __syncthreads();
    if (jt < 63){
      int nb = cur ^ 1;
      tile[nb][lrow][lc4*4+0]=p0.x; tile[nb][lrow][lc4*4+1]=p0.y;
      tile[nb][lrow][lc4*4+2]=p0.z; tile[nb][lrow][lc4*4+3]=p0.w;
      tile[nb][lrow+16][lc4*4+0]=p1.x; tile[nb][lrow+16][lc4*4+1]=p1.y;
      tile[nb][lrow+16][lc4*4+2]=p1.z; tile[nb][lrow+16][lc4*4+3]=p1.w;
      rwt[nb][ljj][lr]=prw0; rwt[nb][ljj+32][lr]=prw1;
      wrt[nb][ljj][lr]=pww0; wrt[nb][ljj+32][lr]=pww1;
      __syncthreads();
    }
  }
  #pragma unroll
  for (int r=0;r<8;r++){
    sred[t][r]    = A0[r]; sred[t][8+r]  = A1[r];
    sred[t][16+r] = B0[r]; sred[t][24+r] = B1[r];
  }
  __syncthreads();
  if (t < 32){
    int rg2 = t & 15, rr = t >> 4;
    int i = i0 + rg2 + 16*rr;
    float Af[8], Bf[8];
    #pragma unroll
    for (int r=0;r<8;r++){ Af[r]=0; Bf[r]=0; }
    for (int g=0; g<16; g++){
      const float* s = sred[g*16 + rg2];
      #pragma unroll
      for (int r=0;r<8;r++){
        Af[r] += s[rr*8 + r];
        Bf[r] += s[16 + rr*8 + r];
      }
    }
    size_t bn = (size_t)b*ND + i;
    float wwi = ww[bn], pi = prec[bn];
    float tii = tb[(size_t)i*ND + i];
    float nfv = nf_p[0];
    #pragma unroll
    for (int r=0;r<8;r++){
      float rwi = rw[bn*RDIM + r];
      float v = (1.f-wwi)*(Af[r] - tii*rwi) - (Bf[r] - tii*wwi*rwi)
              + wwi*(Sp[b*RDIM+r] - pi*rwi);
      fwv[bn*RDIM + r] = nfv * v;
    }
  }
}

// ---------- backward temporal read weights (column pass over tml) ----------
__global__ __launch_bounds__(256) void k_bw(const float* __restrict__ tml,
    const float* __restrict__ rw, const float* __restrict__ wrw,
    const float* __restrict__ ww, const float* __restrict__ prec,
    const float* __restrict__ Sw, const float* __restrict__ nf_p,
    float* __restrict__ bwv){
  __shared__ float tilec[2][64][33];
  __shared__ float rwt[2][64][8];
  __shared__ float wrt[2][64][8];
  __shared__ float sred[256][33];
  int t = threadIdx.x;
  int i0 = blockIdx.x*32;               // column base
  int b = blockIdx.y;
  const float* tb = tml + (size_t)b*ND*ND;
  int cg = t & 15, jg = t >> 4;
  int lrow = t >> 3, lc4 = t & 7;       // tile loader: 64 rows x 8 float4
  int ljj = t >> 3, lr = t & 7;
  float A0[8], A1[8], B0[8], B1[8];
  #pragma unroll
  for (int r=0;r<8;r++){A0[r]=0;A1[r]=0;B0[r]=0;B1[r]=0;}
  {
    const float4 v0 = *(const float4*)(tb + (size_t)(lrow)*ND + i0 + lc4*4);
    const float4 v1 = *(const float4*)(tb + (size_t)(lrow+32)*ND + i0 + lc4*4);
    tilec[0][lrow][lc4*4+0]=v0.x; tilec[0][lrow][lc4*4+1]=v0.y;
    tilec[0][lrow][lc4*4+2]=v0.z; tilec[0][lrow][lc4*4+3]=v0.w;
    tilec[0][lrow+32][lc4*4+0]=v1.x; tilec[0][lrow+32][lc4*4+1]=v1.y;
    tilec[0][lrow+32][lc4*4+2]=v1.z; tilec[0][lrow+32][lc4*4+3]=v1.w;
    rwt[0][ljj][lr]    = rw[((size_t)b*ND + ljj)*RDIM + lr];
    rwt[0][ljj+32][lr] = rw[((size_t)b*ND + ljj+32)*RDIM + lr];
    wrt[0][ljj][lr]    = wrw[((size_t)b*ND + ljj)*RDIM + lr];
    wrt[0][ljj+32][lr] = wrw[((size_t)b*ND + ljj+32)*RDIM + lr];
  }
  __syncthreads();
  float4 p0, p1; float prw0, prw1, pww0, pww1;
  for (int jt=0; jt<64; jt++){
    int cur = jt & 1;
    if (jt < 63){
      int j0 = (jt+1)*64;
      p0 = *(const float4*)(tb + (size_t)(j0+lrow)*ND + i0 + lc4*4);
      p1 = *(const float4*)(tb + (size_t)(j0+lrow+32)*ND + i0 + lc4*4);
      prw0 = rw[((size_t)b*ND + j0+ljj)*RDIM + lr];
      prw1 = rw[((size_t)b*ND + j0+ljj+32)*RDIM + lr];
      pww0 = wrw[((size_t)b*ND + j0+ljj)*RDIM + lr];
      pww1 = wrw[((size_t)b*ND + j0+ljj+32)*RDIM + lr];
    }
    #pragma unroll
    for (int jj=0;jj<4;jj++){
      int j = jg*4 + jj;
      float t0 = tilec[cur][j][cg];
      float t1 = tilec[cur][j][cg+16];
      #pragma unroll
      for (int r=0;r<8;r++){
        float rv_ = rwt[cur][j][r];
        float wv_ = wrt[cur][j][r];
        A0[r] += t0*rv_; B0[r] += t0*wv_;
        A1[r] += t1*rv_; B1[r] += t1*wv_;
      }
    }
    __syncthreads();
    if (jt < 63){
      int nb = cur ^ 1;
      tilec[nb][lrow][lc4*4+0]=p0.x; tilec[nb][lrow][lc4*4+1]=p0.y;
      tilec[nb][lrow][lc4*4+2]=p0.z; tilec[nb][lrow][lc4*4+3]=p0.w;
      tilec[nb][lrow+32][lc4*4+0]=p1.x; tilec[nb][lrow+32][lc4*4+1]=p1.y;
      tilec[nb][lrow+32][lc4*4+2]=p1.z; tilec[nb][lrow+32][lc4*4+3]=p1.w;
      rwt[nb][ljj][lr]=prw0; rwt[nb][ljj+32][lr]=prw1;
      wrt[nb][ljj][lr]=pww0; wrt[nb][ljj+32][lr]=pww1;
      __syncthreads();
    }
  }
  #pragma unroll
  for (int r=0;r<8;r++){
    sred[t][r]    = A0[r]; sred[t][8+r]  = A1[r];
    sred[t][16+r] = B0[r]; sred[t][24+r] = B1[r];
  }
  __syncthreads();
  if (t < 32){
    int cg2 = t & 15, cc = t >> 4;
    int i = i0 + cg2 + 16*cc;
    float Af[8], Bf[8];
    #pragma unroll
    for (int r=0;r<8;r++){ Af[r]=0; Bf[r]=0; }
    for (int g=0; g<16; g++){
      const float* s = sred[g*16 + cg2];
      #pragma unroll
      for (int r=0;r<8;r++){
        Af[r] += s[cc*8 + r];
        Bf[r] += s[16 + cc*8 + r];
      }
    }
    size_t bn = (size_t)b*ND + i;
    float wwi = ww[bn], pi = prec[bn];
    float tii = tb[(size_t)i*ND + i];
    float nfv = nf_p[0];
    #pragma unroll
    for (int r=0;r<8;r++){
      float rwi = rw[bn*RDIM + r];
      float v = (1.f-wwi)*(Af[r] - tii*rwi) - (Bf[r] - tii*wwi*rwi)
              + pi*(Sw[b*RDIM+r] - wwi*rwi);
      bwv[bn*RDIM + r] = nfv * v;
    }
  }
}

// ---------- read content scores ----------
__global__ void k_rcs(const float* __restrict__ nm, const float* __restrict__ rkn,
                      const float* __restrict__ rb, float* __restrict__ rcs){
  int b = blockIdx.y;
  int n = blockIdx.x*256 + threadIdx.x;
  int t = threadIdx.x;
  __shared__ float rk[8][64];
  for (int p=0;p<2;p++){
    int idx = t + p*256; int r = idx>>6, w = idx&63;
    rk[r][w] = rkn[b*512 + r*64 + w];
  }
  __syncthreads();
  const float* m = nm + ((size_t)b*ND+n)*64;
  float nr=0.f; float d[8];
  #pragma unroll
  for (int r=0;r<8;r++) d[r]=0.f;
  for (int w=0;w<64;w++){
    float mv = m[w]; nr += mv*mv;
    #pragma unroll
    for (int r=0;r<8;r++) d[r] += mv*rk[r][w];
  }
  float inv = 1.f/(sqrtf(nr)+EPSF);
  size_t bn = (size_t)b*ND + n;
  #pragma unroll
  for (int r=0;r<8;r++) rcs[bn*8+r] = rb[b*8+r]*d[r]*inv;
}

// ---------- softmax over n for each (b,r) ----------
__global__ void k_rcsm(float* __restrict__ rcs){
  int r = blockIdx.x, b = blockIdx.y;
  int t = threadIdx.x;
  __shared__ float red[256];
  float* base = rcs + (size_t)b*ND*8 + r;
  float mx = -1e30f;
  for (int i=t;i<ND;i+=256) mx = fmaxf(mx, base[(size_t)i*8]);
  red[t]=mx; __syncthreads();
  for (int s=128;s>0;s>>=1){ if (t<s) red[t]=fmaxf(red[t],red[t+s]); __syncthreads(); }
  float gmx = red[0]; __syncthreads();
  float sm=0.f;
  for (int i=t;i<ND;i+=256) sm += expf(base[(size_t)i*8]-gmx);
  red[t]=sm; __syncthreads();
  for (int s=128;s>0;s>>=1){ if (t<s) red[t]+=red[t+s]; __syncthreads(); }
  float inv = 1.f/red[0];
  for (int i=t;i<ND;i+=256) base[(size_t)i*8] = expf(base[(size_t)i*8]-gmx)*inv;
}

// ---------- read vectors: rv[b,w,r] = sum_n nm * (m0*bw + m1*rc + m2*fw) ----------
__global__ void k_rv(const float* __restrict__ nm, const float* __restrict__ fwv,
                     const float* __restrict__ bwv, const float* __restrict__ rcs,
                     const float* __restrict__ md, float* __restrict__ rv){
  int b = blockIdx.y;
  int n0 = blockIdx.x*256;
  int t = threadIdx.x;
  int w = t & 63, rp = t >> 6;
  int r0 = rp*2, r1 = r0+1;
  float m00 = md[(b*8+r0)*3+0], m01 = md[(b*8+r0)*3+1], m02 = md[(b*8+r0)*3+2];
  float m10 = md[(b*8+r1)*3+0], m11 = md[(b*8+r1)*3+1], m12 = md[(b*8+r1)*3+2];
  float acc0=0.f, acc1=0.f;
  for (int nn=0;nn<256;nn++){
    size_t bn = (size_t)b*ND + n0 + nn;
    float mv = nm[bn*64 + w];
    float rw0 = m00*bwv[bn*8+r0] + m01*rcs[bn*8+r0] + m02*fwv[bn*8+r0];
    float rw1 = m10*bwv[bn*8+r1] + m11*rcs[bn*8+r1] + m12*fwv[bn*8+r1];
    acc0 += mv*rw0; acc1 += mv*rw1;
  }
  atomicAdd(&rv[(b*64+w)*8 + r0], acc0);
  atomicAdd(&rv[(b*64+w)*8 + r1], acc1);
}

// ---------- out += rv @ W_r ----------
__global__ void k_wr(const float* __restrict__ rv, const float* __restrict__ W_r,
                     float* __restrict__ out){
  int vc = blockIdx.x, kc = blockIdx.y;  // 16 x 4
  int t = threadIdx.x;
  int v = vc*256 + t;
  __shared__ float s[4][128];
  for (int idx=t; idx<512; idx+=256){ int b=idx>>7, kk=idx&127; s[b][kk]=rv[b*512 + kc*128+kk]; }
  __syncthreads();
  float a0=0,a1=0,a2=0,a3=0;
  for (int kk=0;kk<128;kk++){
    float w = W_r[(size_t)(kc*128+kk)*VTD + v];
    a0 += s[0][kk]*w; a1 += s[1][kk]*w; a2 += s[2][kk]*w; a3 += s[3][kk]*w;
  }
  atomicAdd(&out[0*VTD+v], a0); atomicAdd(&out[1*VTD+v], a1);
  atomicAdd(&out[2*VTD+v], a2); atomicAdd(&out[3*VTD+v], a3);
}

extern "C" void kernel_launch(void* const* d_in, const int* in_sizes, int n_in,
                              void* d_out, int out_size, void* d_ws, size_t ws_size,
                              hipStream_t stream) {
  const float* x_in  = (const float*)d_in[0];
  const float* prec  = (const float*)d_in[1];
  const float* tml   = (const float*)d_in[2];
  const float* memory= (const float*)d_in[3];
  const float* lrw   = (const float*)d_in[4];
  const float* lus   = (const float*)d_in[5];
  const float* lww   = (const float*)d_in[6];
  const float* nf    = (const float*)d_in[7];
  const float* lrv   = (const float*)d_in[8];
  const float* ch    = (const float*)d_in[9];
  const float* cc    = (const float*)d_in[10];
  const float* Wi    = (const float*)d_in[11];
  const float* Wf    = (const float*)d_in[12];
  const float* Wo    = (const float*)d_in[13];
  const float* Wsg   = (const float*)d_in[14];
  const float* b_i   = (const float*)d_in[15];
  const float* b_f   = (const float*)d_in[16];
  const float* b_o   = (const float*)d_in[17];
  const float* b_s   = (const float*)d_in[18];
  const float* W_y   = (const float*)d_in[19];
  const float* W_E   = (const float*)d_in[20];
  const float* W_r   = (const float*)d_in[21];
  float* ws = (float*)d_ws;
  float* out = (float*)d_out;

  hipMemsetAsync(ws, 0, (size_t)ZERO_FLOATS*sizeof(float), stream);
  hipMemsetAsync(out, 0, (size_t)out_size*sizeof(float), stream);

  // controller
  k_pre<<<dim3(7,16),256,0,stream>>>(x_in, lrv, ch, Wi, Wf, Wo, Wsg, ws+OFF_PRE);
  k_hout<<<1,256,0,stream>>>(ws+OFF_PRE, b_i,b_f,b_o,b_s, cc, ws+OFF_FLAT, 0);
  for (int l=1;l<LL;l++){
    k_gprev<<<dim3(2,4),256,0,stream>>>(ws+OFF_FLAT, Wi, Wf, Wo, Wsg, ws+OFF_PRE, l);
    k_hout<<<1,256,0,stream>>>(ws+OFF_PRE, b_i,b_f,b_o,b_s, cc, ws+OFF_FLAT, l);
  }
  // projections
  k_wy<<<dim3(16,8),256,0,stream>>>(ws+OFF_FLAT, W_y, out);
  k_we<<<dim3(3,8),256,0,stream>>>(ws+OFF_FLAT, W_E, ws+OFF_IV);
  k_iface<<<4,256,0,stream>>>(ws+OFF_IV, ws+OFF_WKN, ws+OFF_RKN, ws+OFF_RB, ws+OFF_WB,
                              ws+OFF_ER, ws+OFF_WV, ws+OFF_FR, ws+OFF_AG, ws+OFF_WG, ws+OFF_MD);
  // allocation + content write weights
  k_psiu<<<64,256,0,stream>>>(ws+OFF_FR, lrw, lus, lww, nf, ws+OFF_U);
  k_sort<<<4,1024,0,stream>>>(ws+OFF_U, ws+OFF_AW);
  k_cw<<<4,1024,0,stream>>>(memory, ws+OFF_WKN, ws+OFF_WB, ws+OFF_CW);
  k_ww<<<dim3(16,4),256,0,stream>>>(ws+OFF_AW, ws+OFF_CW, ws+OFF_AG, ws+OFF_WG,
                                    prec, lrw, ws+OFF_WW, ws+OFF_WRW, ws+OFF_SP, ws+OFF_SW);
  k_newmem<<<4096,256,0,stream>>>(memory, ws+OFF_WW, ws+OFF_ER, ws+OFF_WV, ws+OFF_NM);
  // temporal link contractions (the 256MB passes)
  k_fw<<<dim3(128,4),256,0,stream>>>(tml, lrw, ws+OFF_WRW, ws+OFF_WW, prec, ws+OFF_SP, nf, ws+OFF_FWD);
  k_bw<<<dim3(128,4),256,0,stream>>>(tml, lrw, ws+OFF_WRW, ws+OFF_WW, prec, ws+OFF_SW, nf, ws+OFF_BWD);
  // read addressing + readout
  k_rcs<<<dim3(16,4),256,0,stream>>>(ws+OFF_NM, ws+OFF_RKN, ws+OFF_RB, ws+OFF_RCS);
  k_rcsm<<<dim3(8,4),256,0,stream>>>(ws+OFF_RCS);
  k_rv<<<dim3(16,4),256,0,stream>>>(ws+OFF_NM, ws+OFF_FWD, ws+OFF_BWD, ws+OFF_RCS, ws+OFF_MD, ws+OFF_RV);
  k_wr<<<dim3(16,4),256,0,stream>>>(ws+OFF_RV, W_r, out);
}

// Round 2
// 772.255 us; speedup vs baseline: 1.1285x; 1.1285x over previous
//
#include <hip/hip_runtime.h>

#define BSZ 4
#define XD 1024
#define HD 256
#define LL 4
#define VTD 4096
#define WDIM 64
#define RDIM 8
#define ND 4096
#define ETD 747
#define IND 2048
#define EPSF 1e-8f

// ---- workspace layout (float offsets) ----
#define OFF_PRE 0            // [L][4][BS][H] = 16384   (atomic, zeroed)
#define OFF_IV 16384         // [BS][747]               (atomic, zeroed)
#define OFF_SP 19372         // [BS][8]
#define OFF_SW 19404         // [BS][8]
#define OFF_RV 19436         // [BS][64][8] = 2048
#define OFF_CWS 21484        // [BS] write-softmax exp sums
#define OFF_RSS 21488        // [BS][8] read-softmax exp sums
#define ZERO_FLOATS 21520
#define OFF_FLAT 21520       // [BS][1024]
#define OFF_WKN 25616        // [BS][64]
#define OFF_RKN 25872        // [BS][8][64]
#define OFF_RB 27920         // [BS][8]
#define OFF_WB 27952         // [BS]
#define OFF_ER 27956         // [BS][64]
#define OFF_WV 28212         // [BS][64]
#define OFF_FR 28468         // [BS][8]
#define OFF_AG 28500         // [BS]
#define OFF_WG 28504         // [BS]
#define OFF_MD 28508         // [BS][8][3]
#define OFF_U 28604          // [BS][N]
#define OFF_AW 44988         // [BS][N]
#define OFF_CW 61372         // [BS][N]  (raw exp)
#define OFF_WW 77756         // [BS][N]
#define OFF_WRW 94140        // [BS][N][8]
#define OFF_NM 225212        // [BS][N][64]
#define OFF_FWD 1273788      // [BS][N][8]
#define OFF_BWD 1404860      // [BS][N][8]
#define OFF_RCS 1535932      // [BS][N][8] (raw exp)

__device__ __forceinline__ float sigf(float x){ return 1.f/(1.f+expf(-x)); }
__device__ __forceinline__ float splus(float z){ return fmaxf(z,0.f) + log1pf(expf(-fabsf(z))); }

// ---------- LSTM: known-input part of all gates, all layers ----------
__global__ void k_pre(const float* __restrict__ x_in, const float* __restrict__ lrv,
                      const float* __restrict__ ch,
                      const float* __restrict__ Wi, const float* __restrict__ Wf,
                      const float* __restrict__ Wo, const float* __restrict__ Wsg,
                      float* __restrict__ pre){
  int kc = blockIdx.x;          // 0..6 (7 chunks of 256 over k<1792)
  int lg = blockIdx.y;          // 0..15
  int l = lg >> 2, g = lg & 3;
  int t = threadIdx.x;
  __shared__ float s[4][256];
  for (int idx = t; idx < 1024; idx += 256){
    int b = idx >> 8, kk = idx & 255;
    int k = kc*256 + kk;
    float v;
    if (k < 1024)      v = x_in[b*XD + k];
    else if (k < 1536) v = lrv[b*512 + (k-1024)];
    else               v = ch[(b*LL + l)*HD + (k-1536)];
    s[b][kk] = v;
  }
  __syncthreads();
  const float* Wg = (g==0?Wi:g==1?Wf:g==2?Wo:Wsg) + (size_t)l*IND*HD;
  float a0=0,a1=0,a2=0,a3=0;
  for (int kk=0; kk<256; kk++){
    float w = Wg[(size_t)(kc*256+kk)*HD + t];
    a0 += s[0][kk]*w; a1 += s[1][kk]*w; a2 += s[2][kk]*w; a3 += s[3][kk]*w;
  }
  float* p = pre + (size_t)((l*4+g)*4)*HD + t;
  atomicAdd(p + 0*HD, a0); atomicAdd(p + 1*HD, a1);
  atomicAdd(p + 2*HD, a2); atomicAdd(p + 3*HD, a3);
}

// ---------- fused: compute h_{l-1} from pre, then add W.h_{l-1} into pre[l] ----------
__global__ void k_glayer(float* __restrict__ pre,
                         const float* __restrict__ b_i, const float* __restrict__ b_f,
                         const float* __restrict__ b_o, const float* __restrict__ b_s,
                         const float* __restrict__ cc,
                         const float* __restrict__ Wi, const float* __restrict__ Wf,
                         const float* __restrict__ Wo, const float* __restrict__ Wsg,
                         float* __restrict__ flat, int l){
  int t = threadIdx.x;
  int lm = l - 1;
  __shared__ float hs[4][257];
  float bi = b_i[lm*HD+t], bf = b_f[lm*HD+t], bo = b_o[lm*HD+t], bs = b_s[lm*HD+t];
  for (int b=0;b<BSZ;b++){
    float pi = pre[((lm*4+0)*4+b)*HD+t];
    float pf = pre[((lm*4+1)*4+b)*HD+t];
    float po = pre[((lm*4+2)*4+b)*HD+t];
    float ps = pre[((lm*4+3)*4+b)*HD+t];
    float ig = sigf(pi+bi), fg = sigf(pf+bf), og = sigf(po+bo);
    float sg = tanhf(ps+bs);
    float c = fg*cc[(b*LL+lm)*HD+t] + ig*sg;
    float h = og*tanhf(c);
    hs[b][t] = h;
    flat[b*1024 + lm*HD + t] = h;   // all blocks write identical values (benign)
  }
  __syncthreads();
  int kc = blockIdx.x;          // 0..1 (128 k each)
  int g  = blockIdx.y;          // 0..3
  const float* Wg = (g==0?Wi:g==1?Wf:g==2?Wo:Wsg) + (size_t)l*IND*HD;
  float a0=0,a1=0,a2=0,a3=0;
  for (int kk=0; kk<128; kk++){
    int k = kc*128 + kk;
    float w = Wg[(size_t)(1792 + k)*HD + t];
    a0 += hs[0][k]*w; a1 += hs[1][k]*w; a2 += hs[2][k]*w; a3 += hs[3][k]*w;
  }
  float* p = pre + (size_t)((l*4+g)*4)*HD + t;
  atomicAdd(p + 0*HD, a0); atomicAdd(p + 1*HD, a1);
  atomicAdd(p + 2*HD, a2); atomicAdd(p + 3*HD, a3);
}

// ---------- final h (layer 3) ----------
__global__ void k_hfin(const float* __restrict__ pre,
                       const float* __restrict__ b_i, const float* __restrict__ b_f,
                       const float* __restrict__ b_o, const float* __restrict__ b_s,
                       const float* __restrict__ cc, float* __restrict__ flat){
  int t = threadIdx.x;
  int l = 3;
  float bi = b_i[l*HD+t], bf = b_f[l*HD+t], bo = b_o[l*HD+t], bs = b_s[l*HD+t];
  for (int b=0;b<BSZ;b++){
    float pi = pre[((l*4+0)*4+b)*HD+t];
    float pf = pre[((l*4+1)*4+b)*HD+t];
    float po = pre[((l*4+2)*4+b)*HD+t];
    float ps = pre[((l*4+3)*4+b)*HD+t];
    float ig = sigf(pi+bi), fg = sigf(pf+bf), og = sigf(po+bo);
    float sg = tanhf(ps+bs);
    float c = fg*cc[(b*LL+l)*HD+t] + ig*sg;
    flat[b*1024 + l*HD + t] = og*tanhf(c);
  }
}

// ---------- y = flat @ W_y (atomic into out) ----------
__global__ void k_wy(const float* __restrict__ flat, const float* __restrict__ W_y,
                     float* __restrict__ out){
  int vc = blockIdx.x, kc = blockIdx.y;   // 16 x 8
  int t = threadIdx.x;
  int v = vc*256 + t;
  __shared__ float s[4][128];
  for (int idx=t; idx<512; idx+=256){ int b=idx>>7, kk=idx&127; s[b][kk]=flat[b*1024 + kc*128+kk]; }
  __syncthreads();
  float a0=0,a1=0,a2=0,a3=0;
  for (int kk=0;kk<128;kk++){
    float w = W_y[(size_t)(kc*128+kk)*VTD + v];
    a0 += s[0][kk]*w; a1 += s[1][kk]*w; a2 += s[2][kk]*w; a3 += s[3][kk]*w;
  }
  atomicAdd(&out[0*VTD+v], a0); atomicAdd(&out[1*VTD+v], a1);
  atomicAdd(&out[2*VTD+v], a2); atomicAdd(&out[3*VTD+v], a3);
}

// ---------- iv = flat @ W_E ----------
__global__ void k_we(const float* __restrict__ flat, const float* __restrict__ W_E,
                     float* __restrict__ iv){
  int vc = blockIdx.x, kc = blockIdx.y;   // 3 x 8
  int t = threadIdx.x;
  int v = vc*256 + t;
  __shared__ float s[4][128];
  for (int idx=t; idx<512; idx+=256){ int b=idx>>7, kk=idx&127; s[b][kk]=flat[b*1024 + kc*128+kk]; }
  __syncthreads();
  if (v >= ETD) return;
  float a0=0,a1=0,a2=0,a3=0;
  for (int kk=0;kk<128;kk++){
    float w = W_E[(size_t)(kc*128+kk)*ETD + v];
    a0 += s[0][kk]*w; a1 += s[1][kk]*w; a2 += s[2][kk]*w; a3 += s[3][kk]*w;
  }
  atomicAdd(&iv[0*ETD+v], a0); atomicAdd(&iv[1*ETD+v], a1);
  atomicAdd(&iv[2*ETD+v], a2); atomicAdd(&iv[3*ETD+v], a3);
}

// ---------- interface vector post-processing ----------
__global__ void k_iface(const float* __restrict__ iv, float* wkn, float* rkn, float* rb,
                        float* wb, float* er, float* wv, float* fr, float* ag, float* wg,
                        float* md){
  int b = blockIdx.x, t = threadIdx.x;
  const float* ivb = iv + b*ETD;
  __shared__ float rk2[8];
  if (t < 8) rk2[t] = 0.f;
  __syncthreads();
  for (int p=0;p<2;p++){
    int idx = t + p*256; int w = idx>>3, r = idx&7;
    float v = ivb[w*8 + r];
    atomicAdd(&rk2[r], v*v);
  }
  float wkv = 0.f, ss = 0.f;
  if (t < 64){ wkv = ivb[520 + t]; ss = wkv*wkv; }
  for (int o=32;o>0;o>>=1) ss += __shfl_xor(ss, o, 64);
  if (t < 64) wkn[b*64 + t] = wkv/(sqrtf(ss)+EPSF);
  __syncthreads();
  for (int p=0;p<2;p++){
    int idx = t + p*256; int w = idx>>3, r = idx&7;
    float v = ivb[w*8 + r];
    rkn[b*512 + r*64 + w] = v/(sqrtf(rk2[r])+EPSF);
  }
  if (t < 8) rb[b*8+t] = 1.f + splus(-ivb[512+t]);
  if (t == 0) wb[b] = 1.f + splus(-ivb[584]);
  if (t < 64){ er[b*64+t] = sigf(ivb[585+t]); wv[b*64+t] = ivb[649+t]; }
  if (t < 8) fr[b*8+t] = sigf(ivb[713+t]);
  if (t == 0) ag[b] = sigf(ivb[721]);
  if (t == 1) wg[b] = sigf(ivb[722]);
  if (t < 8){
    float m0 = ivb[723+t*3], m1 = ivb[723+t*3+1], m2 = ivb[723+t*3+2];
    float mx = fmaxf(m0, fmaxf(m1,m2));
    float e0 = expf(m0-mx), e1 = expf(m1-mx), e2 = expf(m2-mx);
    float inv = 1.f/(e0+e1+e2);
    md[(b*8+t)*3+0]=e0*inv; md[(b*8+t)*3+1]=e1*inv; md[(b*8+t)*3+2]=e2*inv;
  }
}

// ---------- usage u ----------
__global__ void k_psiu(const float* __restrict__ fr, const float* __restrict__ lrw,
                       const float* __restrict__ lus, const float* __restrict__ lww,
                       const float* __restrict__ nf, float* __restrict__ u){
  int gid = blockIdx.x*256 + threadIdx.x;
  int b = gid >> 12, n = gid & 4095;
  size_t bn = (size_t)b*ND + n;
  float psi = 1.f;
  #pragma unroll
  for (int r=0;r<8;r++) psi *= 1.f - fr[b*8+r]*lrw[bn*8+r];
  float a = lus[bn], c = lww[bn];
  u[bn] = (a + c - a*c)*psi*nf[0];
}

// ---------- allocation weights, sort-free (log-domain rank product) ----------
// stable-argsort cumprod == product of u_j over lexicographically smaller (u_j, j)
__global__ __launch_bounds__(256) void k_alloc(const float* __restrict__ u, float* __restrict__ aw){
  __shared__ unsigned long long key[4096];  // (bits(u)<<32)|j : u>=0 so uint order == float order
  __shared__ float lg[4096];
  __shared__ float part[64][5];
  __shared__ float uloc[64];
  int b = blockIdx.y;
  int i0 = blockIdx.x*64;
  int t = threadIdx.x;
  const float* ub = u + (size_t)b*ND;
  for (int idx=t; idx<4096; idx+=256){
    float uv = ub[idx];
    unsigned int bits = __float_as_uint(uv);
    key[idx] = ((unsigned long long)bits << 32) | (unsigned int)idx;
    lg[idx] = logf(uv);            // logf(0) = -inf -> exp -> 0, matches cumprod
  }
  if (t < 64) uloc[t] = ub[i0+t];
  __syncthreads();
  int il = t & 63, c = t >> 6;
  unsigned long long ki = key[i0+il];
  float s = 0.f;
  int j0 = c*1024;
  #pragma unroll 4
  for (int j=j0; j<j0+1024; j++){
    s += (key[j] < ki) ? lg[j] : 0.f;
  }
  part[il][c] = s;
  __syncthreads();
  if (t < 64){
    float tot = part[t][0]+part[t][1]+part[t][2]+part[t][3];
    aw[(size_t)b*ND + i0 + t] = (1.f - uloc[t]) * expf(tot);
  }
}

// ---------- write content: raw exp scores + global sum (no max-sub: |score|<=~3) ----------
__global__ __launch_bounds__(256) void k_cw1(const float* __restrict__ memory,
                                             const float* __restrict__ wkn,
                                             const float* __restrict__ wb,
                                             float* __restrict__ cw, float* __restrict__ cws){
  int b = blockIdx.y, n0 = blockIdx.x*256, t = threadIdx.x;
  __shared__ float wk[64];
  __shared__ float tile[64][65];
  __shared__ float part[64][9];
  if (t < 64) wk[t] = wkn[b*64+t];
  float wbv = wb[b];
  float esum = 0.f;
  int row = t>>2, q4 = t&3;
  int n_l = t&63, q = t>>6;
  for (int sb=0; sb<4; sb++){
    const float* src = memory + ((size_t)b*ND + n0 + sb*64 + row)*64 + q4*16;
    float4 v0 = *(const float4*)(src+0);
    float4 v1 = *(const float4*)(src+4);
    float4 v2 = *(const float4*)(src+8);
    float4 v3 = *(const float4*)(src+12);
    float* d = &tile[row][q4*16];
    d[0]=v0.x; d[1]=v0.y; d[2]=v0.z; d[3]=v0.w;
    d[4]=v1.x; d[5]=v1.y; d[6]=v1.z; d[7]=v1.w;
    d[8]=v2.x; d[9]=v2.y; d[10]=v2.z; d[11]=v2.w;
    d[12]=v3.x; d[13]=v3.y; d[14]=v3.z; d[15]=v3.w;
    __syncthreads();
    float nr=0.f, dd=0.f;
    #pragma unroll
    for (int w=q*16; w<q*16+16; w++){
      float mv = tile[n_l][w];
      nr += mv*mv; dd += mv*wk[w];
    }
    part[n_l][q] = nr; part[n_l][4+q] = dd;
    __syncthreads();
    if (t < 64){
      float nrt = part[t][0]+part[t][1]+part[t][2]+part[t][3];
      float dt  = part[t][4]+part[t][5]+part[t][6]+part[t][7];
      float e = expf(wbv * dt/(sqrtf(nrt)+EPSF));
      cw[(size_t)b*ND + n0 + sb*64 + t] = e;
      esum += e;
    }
    __syncthreads();
  }
  if (t < 64){
    for (int o=32;o>0;o>>=1) esum += __shfl_xor(esum, o, 64);
    if (t == 0) atomicAdd(&cws[b], esum);
  }
}

// ---------- ww, wrw, Sp, Sw (cw softmax division folded in) ----------
__global__ void k_ww(const float* __restrict__ aw, const float* __restrict__ cw,
                     const float* __restrict__ cws,
                     const float* __restrict__ ag, const float* __restrict__ wg,
                     const float* __restrict__ prec, const float* __restrict__ lrw,
                     float* __restrict__ ww, float* __restrict__ wrw,
                     float* __restrict__ Sp, float* __restrict__ Sw){
  int b = blockIdx.y;
  int n = blockIdx.x*256 + threadIdx.x;
  int t = threadIdx.x;
  __shared__ float ssp[8], ssw[8];
  if (t<8){ ssp[t]=0.f; ssw[t]=0.f; }
  __syncthreads();
  size_t bn = (size_t)b*ND + n;
  float agv = ag[b];
  float invc = 1.f/cws[b];
  float wv = wg[b]*(agv*aw[bn] + (1.f-agv)*cw[bn]*invc);
  ww[bn] = wv;
  float pv = prec[bn];
  #pragma unroll
  for (int r=0;r<8;r++){
    float rr = lrw[bn*8+r];
    float wr = wv*rr;
    wrw[bn*8+r] = wr;
    atomicAdd(&ssp[r], pv*rr);
    atomicAdd(&ssw[r], wr);
  }
  __syncthreads();
  if (t<8){ atomicAdd(&Sp[b*8+t], ssp[t]); atomicAdd(&Sw[b*8+t], ssw[t]); }
}

// ---------- memory update ----------
__global__ void k_newmem(const float* __restrict__ mem, const float* __restrict__ ww,
                         const float* __restrict__ er, const float* __restrict__ wv,
                         float* __restrict__ nm){
  int gid = blockIdx.x*256 + threadIdx.x;
  int b = gid >> 18;
  int rem = gid & 262143;
  int n = rem >> 6, w = rem & 63;
  float wwv = ww[(size_t)b*ND + n];
  nm[gid] = mem[gid]*(1.f - wwv*er[b*64+w]) + wwv*wv[b*64+w];
}

// ---------- forward temporal read weights (row pass, 4 rows/thread) ----------
__global__ __launch_bounds__(256) void k_fw(const float* __restrict__ tml,
    const float* __restrict__ rw, const float* __restrict__ wrw,
    const float* __restrict__ ww, const float* __restrict__ prec,
    const float* __restrict__ Sp, const float* __restrict__ nf_p,
    float* __restrict__ fwv){
  __shared__ float tile[2][32][65];
  __shared__ float rwt[2][64][8];
  __shared__ float wrt[2][64][8];
  __shared__ float sred[256][33];
  int t = threadIdx.x;
  int i0 = blockIdx.x*32;
  int b = blockIdx.y;
  const float* tb = tml + (size_t)b*ND*ND;
  int rg = t & 7, jg = t >> 3;          // rows rg+8k, 2 j per jt
  int lrow = t >> 4, lc4 = t & 15;      // tile loader
  int ljj = t >> 3, lr = t & 7;         // rw loader
  float A[4][8], B[4][8];
  #pragma unroll
  for (int k=0;k<4;k++)
    #pragma unroll
    for (int r=0;r<8;r++){ A[k][r]=0.f; B[k][r]=0.f; }
  {
    const float4 v0 = *(const float4*)(tb + (size_t)(i0+lrow)*ND + lc4*4);
    const float4 v1 = *(const float4*)(tb + (size_t)(i0+lrow+16)*ND + lc4*4);
    tile[0][lrow][lc4*4+0]=v0.x; tile[0][lrow][lc4*4+1]=v0.y;
    tile[0][lrow][lc4*4+2]=v0.z; tile[0][lrow][lc4*4+3]=v0.w;
    tile[0][lrow+16][lc4*4+0]=v1.x; tile[0][lrow+16][lc4*4+1]=v1.y;
    tile[0][lrow+16][lc4*4+2]=v1.z; tile[0][lrow+16][lc4*4+3]=v1.w;
    rwt[0][ljj][lr]    = rw[((size_t)b*ND + ljj)*RDIM + lr];
    rwt[0][ljj+32][lr] = rw[((size_t)b*ND + ljj+32)*RDIM + lr];
    wrt[0][ljj][lr]    = wrw[((size_t)b*ND + ljj)*RDIM + lr];
    wrt[0][ljj+32][lr] = wrw[((size_t)b*ND + ljj+32)*RDIM + lr];
  }
  __syncthreads();
  float4 p0, p1; float prw0, prw1, pww0, pww1;
  for (int jt=0; jt<64; jt++){
    int cur = jt & 1;
    if (jt < 63){
      int j0 = (jt+1)*64;
      p0 = *(const float4*)(tb + (size_t)(i0+lrow)*ND + j0 + lc4*4);
      p1 = *(const float4*)(tb + (size_t)(i0+lrow+16)*ND + j0 + lc4*4);
      prw0 = rw[((size_t)b*ND + j0+ljj)*RDIM + lr];
      prw1 = rw[((size_t)b*ND + j0+ljj+32)*RDIM + lr];
      pww0 = wrw[((size_t)b*ND + j0+ljj)*RDIM + lr];
      pww1 = wrw[((size_t)b*ND + j0+ljj+32)*RDIM + lr];
    }
    #pragma unroll
    for (int jj=0;jj<2;jj++){
      int j = jg*2 + jj;
      float t0 = tile[cur][rg][j];
      float t1 = tile[cur][rg+8][j];
      float t2 = tile[cur][rg+16][j];
      float t3 = tile[cur][rg+24][j];
      const float4 ra = *(const float4*)&rwt[cur][j][0];
      const float4 rb4 = *(const float4*)&rwt[cur][j][4];
      const float4 wa = *(const float4*)&wrt[cur][j][0];
      const float4 wb4 = *(const float4*)&wrt[cur][j][4];
      float rv8[8] = {ra.x,ra.y,ra.z,ra.w,rb4.x,rb4.y,rb4.z,rb4.w};
      float wv8[8] = {wa.x,wa.y,wa.z,wa.w,wb4.x,wb4.y,wb4.z,wb4.w};
      #pragma unroll
      for (int r=0;r<8;r++){
        A[0][r] += t0*rv8[r]; A[1][r] += t1*rv8[r]; A[2][r] += t2*rv8[r]; A[3][r] += t3*rv8[r];
        B[0][r] += t0*wv8[r]; B[1][r] += t1*wv8[r]; B[2][r] += t2*wv8[r]; B[3][r] += t3*wv8[r];
      }
    }
    __syncthreads();
    if (jt < 63){
      int nb = cur ^ 1;
      tile[nb][lrow][lc4*4+0]=p0.x; tile[nb][lrow][lc4*4+1]=p0.y;
      tile[nb][lrow][lc4*4+2]=p0.z; tile[nb][lrow][lc4*4+3]=p0.w;
      tile[nb][lrow+16][lc4*4+0]=p1.x; tile[nb][lrow+16][lc4*4+1]=p1.y;
      tile[nb][lrow+16][lc4*4+2]=p1.z; tile[nb][lrow+16][lc4*4+3]=p1.w;
      rwt[nb][ljj][lr]=prw0; rwt[nb][ljj+32][lr]=prw1;
      wrt[nb][ljj][lr]=pww0; wrt[nb][ljj+32][lr]=pww1;
      __syncthreads();
    }
  }
  // two-phase cross-thread reduction (A then B) to fit sred
  #pragma unroll
  for (int k=0;k<4;k++)
    #pragma unroll
    for (int r=0;r<8;r++) sred[t][k*8+r] = A[k][r];
  __syncthreads();
  float Af[8];
  int rg2 = t & 7, k2 = t >> 3;
  if (t < 32){
    #pragma unroll
    for (int r=0;r<8;r++) Af[r]=0.f;
    for (int g=0; g<32; g++){
      const float* s = sred[g*8 + rg2];
      #pragma unroll
      for (int r=0;r<8;r++) Af[r] += s[k2*8 + r];
    }
  }
  __syncthreads();
  #pragma unroll
  for (int k=0;k<4;k++)
    #pragma unroll
    for (int r=0;r<8;r++) sred[t][k*8+r] = B[k][r];
  __syncthreads();
  if (t < 32){
    float Bf[8];
    #pragma unroll
    for (int r=0;r<8;r++) Bf[r]=0.f;
    for (int g=0; g<32; g++){
      const float* s = sred[g*8 + rg2];
      #pragma unroll
      for (int r=0;r<8;r++) Bf[r] += s[k2*8 + r];
    }
    int i = i0 + rg2 + 8*k2;
    size_t bn = (size_t)b*ND + i;
    float wwi = ww[bn], pi = prec[bn];
    float tii = tb[(size_t)i*ND + i];
    float nfv = nf_p[0];
    #pragma unroll
    for (int r=0;r<8;r++){
      float rwi = rw[bn*RDIM + r];
      float v = (1.f-wwi)*(Af[r] - tii*rwi) - (Bf[r] - tii*wwi*rwi)
              + wwi*(Sp[b*RDIM+r] - pi*rwi);
      fwv[bn*RDIM + r] = nfv * v;
    }
  }
}

// ---------- backward temporal read weights (column pass, 4 cols/thread) ----------
__global__ __launch_bounds__(256) void k_bw(const float* __restrict__ tml,
    const float* __restrict__ rw, const float* __restrict__ wrw,
    const float* __restrict__ ww, const float* __restrict__ prec,
    const float* __restrict__ Sw, const float* __restrict__ nf_p,
    float* __restrict__ bwv){
  __shared__ float tilec[2][64][33];
  __shared__ float rwt[2][64][8];
  __shared__ float wrt[2][64][8];
  __shared__ float sred[256][33];
  int t = threadIdx.x;
  int i0 = blockIdx.x*32;               // column base
  int b = blockIdx.y;
  const float* tb = tml + (size_t)b*ND*ND;
  int cg = t & 7, jg = t >> 3;
  int lrow = t >> 3, lc4 = t & 7;       // tile loader: 64 rows x 8 float4
  int ljj = t >> 3, lr = t & 7;
  float A[4][8], B[4][8];
  #pragma unroll
  for (int k=0;k<4;k++)
    #pragma unroll
    for (int r=0;r<8;r++){ A[k][r]=0.f; B[k][r]=0.f; }
  {
    const float4 v0 = *(const float4*)(tb + (size_t)(lrow)*ND + i0 + lc4*4);
    const float4 v1 = *(const float4*)(tb + (size_t)(lrow+32)*ND + i0 + lc4*4);
    tilec[0][lrow][lc4*4+0]=v0.x; tilec[0][lrow][lc4*4+1]=v0.y;
    tilec[0][lrow][lc4*4+2]=v0.z; tilec[0][lrow][lc4*4+3]=v0.w;
    tilec[0][lrow+32][lc4*4+0]=v1.x; tilec[0][lrow+32][lc4*4+1]=v1.y;
    tilec[0][lrow+32][lc4*4+2]=v1.z; tilec[0][lrow+32][lc4*4+3]=v1.w;
    rwt[0][ljj][lr]    = rw[((size_t)b*ND + ljj)*RDIM + lr];
    rwt[0][ljj+32][lr] = rw[((size_t)b*ND + ljj+32)*RDIM + lr];
    wrt[0][ljj][lr]    = wrw[((size_t)b*ND + ljj)*RDIM + lr];
    wrt[0][ljj+32][lr] = wrw[((size_t)b*ND + ljj+32)*RDIM + lr];
  }
  __syncthreads();
  float4 p0, p1; float prw0, prw1, pww0, pww1;
  for (int jt=0; jt<64; jt++){
    int cur = jt & 1;
    if (jt < 63){
      int j0 = (jt+1)*64;
      p0 = *(const float4*)(tb + (size_t)(j0+lrow)*ND + i0 + lc4*4);
      p1 = *(const float4*)(tb + (size_t)(j0+lrow+32)*ND + i0 + lc4*4);
      prw0 = rw[((size_t)b*ND + j0+ljj)*RDIM + lr];
      prw1 = rw[((size_t)b*ND + j0+ljj+32)*RDIM + lr];
      pww0 = wrw[((size_t)b*ND + j0+ljj)*RDIM + lr];
      pww1 = wrw[((size_t)b*ND + j0+ljj+32)*RDIM + lr];
    }
    #pragma unroll
    for (int jj=0;jj<2;jj++){
      int j = jg*2 + jj;
      float t0 = tilec[cur][j][cg];
      float t1 = tilec[cur][j][cg+8];
      float t2 = tilec[cur][j][cg+16];
      float t3 = tilec[cur][j][cg+24];
      const float4 ra = *(const float4*)&rwt[cur][j][0];
      const float4 rb4 = *(const float4*)&rwt[cur][j][4];
      const float4 wa = *(const float4*)&wrt[cur][j][0];
      const float4 wb4 = *(const float4*)&wrt[cur][j][4];
      float rv8[8] = {ra.x,ra.y,ra.z,ra.w,rb4.x,rb4.y,rb4.z,rb4.w};
      float wv8[8] = {wa.x,wa.y,wa.z,wa.w,wb4.x,wb4.y,wb4.z,wb4.w};
      #pragma unroll
      for (int r=0;r<8;r++){
        A[0][r] += t0*rv8[r]; A[1][r] += t1*rv8[r]; A[2][r] += t2*rv8[r]; A[3][r] += t3*rv8[r];
        B[0][r] += t0*wv8[r]; B[1][r] += t1*wv8[r]; B[2][r] += t2*wv8[r]; B[3][r] += t3*wv8[r];
      }
    }
    __syncthreads();
    if (jt < 63){
      int nb = cur ^ 1;
      tilec[nb][lrow][lc4*4+0]=p0.x; tilec[nb][lrow][lc4*4+1]=p0.y;
      tilec[nb][lrow][lc4*4+2]=p0.z; tilec[nb][lrow][lc4*4+3]=p0.w;
      tilec[nb][lrow+32][lc4*4+0]=p1.x; tilec[nb][lrow+32][lc4*4+1]=p1.y;
      tilec[nb][lrow+32][lc4*4+2]=p1.z; tilec[nb][lrow+32][lc4*4+3]=p1.w;
      rwt[nb][ljj][lr]=prw0; rwt[nb][ljj+32][lr]=prw1;
      wrt[nb][ljj][lr]=pww0; wrt[nb][ljj+32][lr]=pww1;
      __syncthreads();
    }
  }
  #pragma unroll
  for (int k=0;k<4;k++)
    #pragma unroll
    for (int r=0;r<8;r++) sred[t][k*8+r] = A[k][r];
  __syncthreads();
  float Af[8];
  int cg2 = t & 7, k2 = t >> 3;
  if (t < 32){
    #pragma unroll
    for (int r=0;r<8;r++) Af[r]=0.f;
    for (int g=0; g<32; g++){
      const float* s = sred[g*8 + cg2];
      #pragma unroll
      for (int r=0;r<8;r++) Af[r] += s[k2*8 + r];
    }
  }
  __syncthreads();
  #pragma unroll
  for (int k=0;k<4;k++)
    #pragma unroll
    for (int r=0;r<8;r++) sred[t][k*8+r] = B[k][r];
  __syncthreads();
  if (t < 32){
    float Bf[8];
    #pragma unroll
    for (int r=0;r<8;r++) Bf[r]=0.f;
    for (int g=0; g<32; g++){
      const float* s = sred[g*8 + cg2];
      #pragma unroll
      for (int r=0;r<8;r++) Bf[r] += s[k2*8 + r];
    }
    int i = i0 + cg2 + 8*k2;
    size_t bn = (size_t)b*ND + i;
    float wwi = ww[bn], pi = prec[bn];
    float tii = tb[(size_t)i*ND + i];
    float nfv = nf_p[0];
    #pragma unroll
    for (int r=0;r<8;r++){
      float rwi = rw[bn*RDIM + r];
      float v = (1.f-wwi)*(Af[r] - tii*rwi) - (Bf[r] - tii*wwi*rwi)
              + pi*(Sw[b*RDIM+r] - wwi*rwi);
      bwv[bn*RDIM + r] = nfv * v;
    }
  }
}

// ---------- read content: raw exp + per-(b,r) sums (no max-sub) ----------
__global__ __launch_bounds__(256) void k_rcs(const float* __restrict__ nm,
                                             const float* __restrict__ rkn,
                                             const float* __restrict__ rb,
                                             float* __restrict__ rcs, float* __restrict__ rss){
  int b = blockIdx.y, n0 = blockIdx.x*256, t = threadIdx.x;
  __shared__ float rk[8][64];
  __shared__ float tile[64][65];
  __shared__ float part[64][37];
  for (int p=0;p<2;p++){ int idx=t+p*256; rk[idx>>6][idx&63] = rkn[b*512 + idx]; }
  float rbv[8];
  #pragma unroll
  for (int r=0;r<8;r++) rbv[r] = rb[b*8+r];
  float es[8];
  #pragma unroll
  for (int r=0;r<8;r++) es[r]=0.f;
  int row = t>>2, q4 = t&3;
  int n_l = t&63, q = t>>6;
  for (int sb=0; sb<4; sb++){
    const float* src = nm + ((size_t)b*ND + n0 + sb*64 + row)*64 + q4*16;
    float4 v0 = *(const float4*)(src+0);
    float4 v1 = *(const float4*)(src+4);
    float4 v2 = *(const float4*)(src+8);
    float4 v3 = *(const float4*)(src+12);
    float* d = &tile[row][q4*16];
    d[0]=v0.x; d[1]=v0.y; d[2]=v0.z; d[3]=v0.w;
    d[4]=v1.x; d[5]=v1.y; d[6]=v1.z; d[7]=v1.w;
    d[8]=v2.x; d[9]=v2.y; d[10]=v2.z; d[11]=v2.w;
    d[12]=v3.x; d[13]=v3.y; d[14]=v3.z; d[15]=v3.w;
    __syncthreads();
    float nr=0.f, dd[8];
    #pragma unroll
    for (int r=0;r<8;r++) dd[r]=0.f;
    #pragma unroll
    for (int w=q*16; w<q*16+16; w++){
      float mv = tile[n_l][w];
      nr += mv*mv;
      #pragma unroll
      for (int r=0;r<8;r++) dd[r] += mv*rk[r][w];
    }
    part[n_l][q*9] = nr;
    #pragma unroll
    for (int r=0;r<8;r++) part[n_l][q*9+1+r] = dd[r];
    __syncthreads();
    if (t < 64){
      float nrt = part[t][0]+part[t][9]+part[t][18]+part[t][27];
      float inv = 1.f/(sqrtf(nrt)+EPSF);
      size_t bn = (size_t)b*ND + n0 + sb*64 + t;
      float ev[8];
      #pragma unroll
      for (int r=0;r<8;r++){
        float dt = part[t][1+r]+part[t][10+r]+part[t][19+r]+part[t][28+r];
        ev[r] = expf(rbv[r]*dt*inv);
        es[r] += ev[r];
      }
      float4* dst = (float4*)(rcs + bn*8);
      dst[0] = make_float4(ev[0],ev[1],ev[2],ev[3]);
      dst[1] = make_float4(ev[4],ev[5],ev[6],ev[7]);
    }
    __syncthreads();
  }
  if (t < 64){
    #pragma unroll
    for (int r=0;r<8;r++){
      float v = es[r];
      for (int o=32;o>0;o>>=1) v += __shfl_xor(v, o, 64);
      if (t == 0) atomicAdd(&rss[b*8+r], v);
    }
  }
}

// ---------- read vectors (rc softmax division folded in) ----------
__global__ void k_rv(const float* __restrict__ nm, const float* __restrict__ fwv,
                     const float* __restrict__ bwv, const float* __restrict__ rcs,
                     const float* __restrict__ rss,
                     const float* __restrict__ md, float* __restrict__ rv){
  int b = blockIdx.y;
  int n0 = blockIdx.x*256;
  int t = threadIdx.x;
  int w = t & 63, rp = t >> 6;
  int r0 = rp*2, r1 = r0+1;
  float m00 = md[(b*8+r0)*3+0], m01 = md[(b*8+r0)*3+1], m02 = md[(b*8+r0)*3+2];
  float m10 = md[(b*8+r1)*3+0], m11 = md[(b*8+r1)*3+1], m12 = md[(b*8+r1)*3+2];
  m01 *= 1.f/rss[b*8+r0];
  m11 *= 1.f/rss[b*8+r1];
  float acc0=0.f, acc1=0.f;
  for (int nn=0;nn<256;nn++){
    size_t bn = (size_t)b*ND + n0 + nn;
    float mv = nm[bn*64 + w];
    float rw0 = m00*bwv[bn*8+r0] + m01*rcs[bn*8+r0] + m02*fwv[bn*8+r0];
    float rw1 = m10*bwv[bn*8+r1] + m11*rcs[bn*8+r1] + m12*fwv[bn*8+r1];
    acc0 += mv*rw0; acc1 += mv*rw1;
  }
  atomicAdd(&rv[(b*64+w)*8 + r0], acc0);
  atomicAdd(&rv[(b*64+w)*8 + r1], acc1);
}

// ---------- out += rv @ W_r ----------
__global__ void k_wr(const float* __restrict__ rv, const float* __restrict__ W_r,
                     float* __restrict__ out){
  int vc = blockIdx.x, kc = blockIdx.y;  // 16 x 4
  int t = threadIdx.x;
  int v = vc*256 + t;
  __shared__ float s[4][128];
  for (int idx=t; idx<512; idx+=256){ int b=idx>>7, kk=idx&127; s[b][kk]=rv[b*512 + kc*128+kk]; }
  __syncthreads();
  float a0=0,a1=0,a2=0,a3=0;
  for (int kk=0;kk<128;kk++){
    float w = W_r[(size_t)(kc*128+kk)*VTD + v];
    a0 += s[0][kk]*w; a1 += s[1][kk]*w; a2 += s[2][kk]*w; a3 += s[3][kk]*w;
  }
  atomicAdd(&out[0*VTD+v], a0); atomicAdd(&out[1*VTD+v], a1);
  atomicAdd(&out[2*VTD+v], a2); atomicAdd(&out[3*VTD+v], a3);
}

extern "C" void kernel_launch(void* const* d_in, const int* in_sizes, int n_in,
                              void* d_out, int out_size, void* d_ws, size_t ws_size,
                              hipStream_t stream) {
  const float* x_in  = (const float*)d_in[0];
  const float* prec  = (const float*)d_in[1];
  const float* tml   = (const float*)d_in[2];
  const float* memory= (const float*)d_in[3];
  const float* lrw   = (const float*)d_in[4];
  const float* lus   = (const float*)d_in[5];
  const float* lww   = (const float*)d_in[6];
  const float* nf    = (const float*)d_in[7];
  const float* lrv   = (const float*)d_in[8];
  const float* ch    = (const float*)d_in[9];
  const float* cc    = (const float*)d_in[10];
  const float* Wi    = (const float*)d_in[11];
  const float* Wf    = (const float*)d_in[12];
  const float* Wo    = (const float*)d_in[13];
  const float* Wsg   = (const float*)d_in[14];
  const float* b_i   = (const float*)d_in[15];
  const float* b_f   = (const float*)d_in[16];
  const float* b_o   = (const float*)d_in[17];
  const float* b_s   = (const float*)d_in[18];
  const float* W_y   = (const float*)d_in[19];
  const float* W_E   = (const float*)d_in[20];
  const float* W_r   = (const float*)d_in[21];
  float* ws = (float*)d_ws;
  float* out = (float*)d_out;

  hipMemsetAsync(ws, 0, (size_t)ZERO_FLOATS*sizeof(float), stream);
  hipMemsetAsync(out, 0, (size_t)out_size*sizeof(float), stream);

  // controller (5 launches instead of 9)
  k_pre<<<dim3(7,16),256,0,stream>>>(x_in, lrv, ch, Wi, Wf, Wo, Wsg, ws+OFF_PRE);
  for (int l=1;l<LL;l++)
    k_glayer<<<dim3(2,4),256,0,stream>>>(ws+OFF_PRE, b_i,b_f,b_o,b_s, cc,
                                         Wi, Wf, Wo, Wsg, ws+OFF_FLAT, l);
  k_hfin<<<1,256,0,stream>>>(ws+OFF_PRE, b_i,b_f,b_o,b_s, cc, ws+OFF_FLAT);
  // projections
  k_wy<<<dim3(16,8),256,0,stream>>>(ws+OFF_FLAT, W_y, out);
  k_we<<<dim3(3,8),256,0,stream>>>(ws+OFF_FLAT, W_E, ws+OFF_IV);
  k_iface<<<4,256,0,stream>>>(ws+OFF_IV, ws+OFF_WKN, ws+OFF_RKN, ws+OFF_RB, ws+OFF_WB,
                              ws+OFF_ER, ws+OFF_WV, ws+OFF_FR, ws+OFF_AG, ws+OFF_WG, ws+OFF_MD);
  // allocation (sort-free) + content write weights
  k_psiu<<<64,256,0,stream>>>(ws+OFF_FR, lrw, lus, lww, nf, ws+OFF_U);
  k_alloc<<<dim3(64,4),256,0,stream>>>(ws+OFF_U, ws+OFF_AW);
  k_cw1<<<dim3(16,4),256,0,stream>>>(memory, ws+OFF_WKN, ws+OFF_WB, ws+OFF_CW, ws+OFF_CWS);
  k_ww<<<dim3(16,4),256,0,stream>>>(ws+OFF_AW, ws+OFF_CW, ws+OFF_CWS, ws+OFF_AG, ws+OFF_WG,
                                    prec, lrw, ws+OFF_WW, ws+OFF_WRW, ws+OFF_SP, ws+OFF_SW);
  k_newmem<<<4096,256,0,stream>>>(memory, ws+OFF_WW, ws+OFF_ER, ws+OFF_WV, ws+OFF_NM);
  // temporal link contractions (the 256MB passes)
  k_fw<<<dim3(128,4),256,0,stream>>>(tml, lrw, ws+OFF_WRW, ws+OFF_WW, prec, ws+OFF_SP, nf, ws+OFF_FWD);
  k_bw<<<dim3(128,4),256,0,stream>>>(tml, lrw, ws+OFF_WRW, ws+OFF_WW, prec, ws+OFF_SW, nf, ws+OFF_BWD);
  // read addressing + readout
  k_rcs<<<dim3(16,4),256,0,stream>>>(ws+OFF_NM, ws+OFF_RKN, ws+OFF_RB, ws+OFF_RCS, ws+OFF_RSS);
  k_rv<<<dim3(16,4),256,0,stream>>>(ws+OFF_NM, ws+OFF_FWD, ws+OFF_BWD, ws+OFF_RCS, ws+OFF_RSS,
                                    ws+OFF_MD, ws+OFF_RV);
  k_wr<<<dim3(16,4),256,0,stream>>>(ws+OFF_RV, W_r, out);
}

// Round 3
// 700.588 us; speedup vs baseline: 1.2439x; 1.1023x over previous
//
#include <hip/hip_runtime.h>

#define BSZ 4
#define XD 1024
#define HD 256
#define LL 4
#define VTD 4096
#define WDIM 64
#define RDIM 8
#define ND 4096
#define ETD 747
#define IND 2048
#define EPSF 1e-8f

// ---- workspace layout (float offsets) ----
// zeroed (atomic targets):
#define OFF_PRE 0            // [L][4][BS][H] = 16384
#define OFF_IV 16384         // [BS][747] = 2988
#define OFF_SP 19372         // [BS][8]
#define OFF_SW 19404         // [BS][8]
#define OFF_RVD 19436        // [BS][64][8] directional partial
#define OFF_RVC 21484        // [BS][64][8] content partial
#define OFF_CWS 23532        // [BS]
#define OFF_RSS 23536        // [BS][8]
#define ZERO_FLOATS 23568
// not zeroed:
#define OFF_FLAT 23568       // [BS][1024]
#define OFF_WKN 27664        // [BS][64]
#define OFF_RKN 27920        // [BS][8][64]
#define OFF_RB 29968         // [BS][8]
#define OFF_WB 30000         // [BS]
#define OFF_ER 30004         // [BS][64]
#define OFF_WV 30260         // [BS][64]
#define OFF_FR 30516         // [BS][8]
#define OFF_AG 30548         // [BS]
#define OFF_WG 30552         // [BS]
#define OFF_MD 30556         // [BS][8][3]
#define OFF_AW 30652         // [BS][N]
#define OFF_CW 47036         // [BS][N] raw exp
#define OFF_WW 63420         // [BS][N]
#define OFF_WRW 79804        // [BS][N][8]
#define OFF_NM 210876        // [BS][N][64]
#define OFF_FWD 1259452      // [BS][N][8]
#define OFF_BWD 1390524      // [BS][N][8]

__device__ __forceinline__ float sigf(float x){ return 1.f/(1.f+expf(-x)); }
__device__ __forceinline__ float splus(float z){ return fmaxf(z,0.f) + log1pf(expf(-fabsf(z))); }

// ---------- LSTM: known-input part of all gates, all layers ----------
__global__ void k_pre(const float* __restrict__ x_in, const float* __restrict__ lrv,
                      const float* __restrict__ ch,
                      const float* __restrict__ Wi, const float* __restrict__ Wf,
                      const float* __restrict__ Wo, const float* __restrict__ Wsg,
                      float* __restrict__ pre){
  int kc = blockIdx.x;          // 0..6
  int lg = blockIdx.y;          // 0..15
  int l = lg >> 2, g = lg & 3;
  int t = threadIdx.x;
  __shared__ float s[4][256];
  for (int idx = t; idx < 1024; idx += 256){
    int b = idx >> 8, kk = idx & 255;
    int k = kc*256 + kk;
    float v;
    if (k < 1024)      v = x_in[b*XD + k];
    else if (k < 1536) v = lrv[b*512 + (k-1024)];
    else               v = ch[(b*LL + l)*HD + (k-1536)];
    s[b][kk] = v;
  }
  __syncthreads();
  const float* Wg = (g==0?Wi:g==1?Wf:g==2?Wo:Wsg) + (size_t)l*IND*HD;
  float a0=0,a1=0,a2=0,a3=0;
  for (int kk=0; kk<256; kk++){
    float w = Wg[(size_t)(kc*256+kk)*HD + t];
    a0 += s[0][kk]*w; a1 += s[1][kk]*w; a2 += s[2][kk]*w; a3 += s[3][kk]*w;
  }
  float* p = pre + (size_t)((l*4+g)*4)*HD + t;
  atomicAdd(p + 0*HD, a0); atomicAdd(p + 1*HD, a1);
  atomicAdd(p + 2*HD, a2); atomicAdd(p + 3*HD, a3);
}

// ---------- fused: h_{l-1} from pre, add W.h_{l-1} into pre[l] ----------
__global__ void k_glayer(float* __restrict__ pre,
                         const float* __restrict__ b_i, const float* __restrict__ b_f,
                         const float* __restrict__ b_o, const float* __restrict__ b_s,
                         const float* __restrict__ cc,
                         const float* __restrict__ Wi, const float* __restrict__ Wf,
                         const float* __restrict__ Wo, const float* __restrict__ Wsg,
                         float* __restrict__ flat, int l){
  int t = threadIdx.x;
  int lm = l - 1;
  __shared__ float hs[4][257];
  float bi = b_i[lm*HD+t], bf = b_f[lm*HD+t], bo = b_o[lm*HD+t], bs = b_s[lm*HD+t];
  for (int b=0;b<BSZ;b++){
    float pi = pre[((lm*4+0)*4+b)*HD+t];
    float pf = pre[((lm*4+1)*4+b)*HD+t];
    float po = pre[((lm*4+2)*4+b)*HD+t];
    float ps = pre[((lm*4+3)*4+b)*HD+t];
    float ig = sigf(pi+bi), fg = sigf(pf+bf), og = sigf(po+bo);
    float sg = tanhf(ps+bs);
    float c = fg*cc[(b*LL+lm)*HD+t] + ig*sg;
    float h = og*tanhf(c);
    hs[b][t] = h;
    flat[b*1024 + lm*HD + t] = h;
  }
  __syncthreads();
  int kc = blockIdx.x;          // 0..1
  int g  = blockIdx.y;          // 0..3
  const float* Wg = (g==0?Wi:g==1?Wf:g==2?Wo:Wsg) + (size_t)l*IND*HD;
  float a0=0,a1=0,a2=0,a3=0;
  for (int kk=0; kk<128; kk++){
    int k = kc*128 + kk;
    float w = Wg[(size_t)(1792 + k)*HD + t];
    a0 += hs[0][k]*w; a1 += hs[1][k]*w; a2 += hs[2][k]*w; a3 += hs[3][k]*w;
  }
  float* p = pre + (size_t)((l*4+g)*4)*HD + t;
  atomicAdd(p + 0*HD, a0); atomicAdd(p + 1*HD, a1);
  atomicAdd(p + 2*HD, a2); atomicAdd(p + 3*HD, a3);
}

// ---------- final h (layer 3) ----------
__global__ void k_hfin(const float* __restrict__ pre,
                       const float* __restrict__ b_i, const float* __restrict__ b_f,
                       const float* __restrict__ b_o, const float* __restrict__ b_s,
                       const float* __restrict__ cc, float* __restrict__ flat){
  int t = threadIdx.x;
  int l = 3;
  float bi = b_i[l*HD+t], bf = b_f[l*HD+t], bo = b_o[l*HD+t], bs = b_s[l*HD+t];
  for (int b=0;b<BSZ;b++){
    float pi = pre[((l*4+0)*4+b)*HD+t];
    float pf = pre[((l*4+1)*4+b)*HD+t];
    float po = pre[((l*4+2)*4+b)*HD+t];
    float ps = pre[((l*4+3)*4+b)*HD+t];
    float ig = sigf(pi+bi), fg = sigf(pf+bf), og = sigf(po+bo);
    float sg = tanhf(ps+bs);
    float c = fg*cc[(b*LL+l)*HD+t] + ig*sg;
    flat[b*1024 + l*HD + t] = og*tanhf(c);
  }
}

// ---------- merged projections: y = flat@W_y (->out), iv = flat@W_E ----------
__global__ void k_proj(const float* __restrict__ flat, const float* __restrict__ W_y,
                       const float* __restrict__ W_E,
                       float* __restrict__ out, float* __restrict__ iv){
  int bx = blockIdx.x, kc = blockIdx.y;   // bx 0..18, kc 0..7
  int t = threadIdx.x;
  __shared__ float s[4][128];
  for (int idx=t; idx<512; idx+=256){ int b=idx>>7, kk=idx&127; s[b][kk]=flat[b*1024 + kc*128+kk]; }
  __syncthreads();
  float a0=0,a1=0,a2=0,a3=0;
  if (bx < 16){
    int v = bx*256 + t;
    for (int kk=0;kk<128;kk++){
      float w = W_y[(size_t)(kc*128+kk)*VTD + v];
      a0 += s[0][kk]*w; a1 += s[1][kk]*w; a2 += s[2][kk]*w; a3 += s[3][kk]*w;
    }
    atomicAdd(&out[0*VTD+v], a0); atomicAdd(&out[1*VTD+v], a1);
    atomicAdd(&out[2*VTD+v], a2); atomicAdd(&out[3*VTD+v], a3);
  } else {
    int v = (bx-16)*256 + t;
    if (v >= ETD) return;
    for (int kk=0;kk<128;kk++){
      float w = W_E[(size_t)(kc*128+kk)*ETD + v];
      a0 += s[0][kk]*w; a1 += s[1][kk]*w; a2 += s[2][kk]*w; a3 += s[3][kk]*w;
    }
    atomicAdd(&iv[0*ETD+v], a0); atomicAdd(&iv[1*ETD+v], a1);
    atomicAdd(&iv[2*ETD+v], a2); atomicAdd(&iv[3*ETD+v], a3);
  }
}

// ---------- interface vector post-processing ----------
__global__ void k_iface(const float* __restrict__ iv, float* wkn, float* rkn, float* rb,
                        float* wb, float* er, float* wv, float* fr, float* ag, float* wg,
                        float* md){
  int b = blockIdx.x, t = threadIdx.x;
  const float* ivb = iv + b*ETD;
  __shared__ float rk2[8];
  if (t < 8) rk2[t] = 0.f;
  __syncthreads();
  for (int p=0;p<2;p++){
    int idx = t + p*256; int w = idx>>3, r = idx&7;
    float v = ivb[w*8 + r];
    atomicAdd(&rk2[r], v*v);
  }
  float wkv = 0.f, ss = 0.f;
  if (t < 64){ wkv = ivb[520 + t]; ss = wkv*wkv; }
  for (int o=32;o>0;o>>=1) ss += __shfl_xor(ss, o, 64);
  if (t < 64) wkn[b*64 + t] = wkv/(sqrtf(ss)+EPSF);
  __syncthreads();
  for (int p=0;p<2;p++){
    int idx = t + p*256; int w = idx>>3, r = idx&7;
    float v = ivb[w*8 + r];
    rkn[b*512 + r*64 + w] = v/(sqrtf(rk2[r])+EPSF);
  }
  if (t < 8) rb[b*8+t] = 1.f + splus(-ivb[512+t]);
  if (t == 0) wb[b] = 1.f + splus(-ivb[584]);
  if (t < 64){ er[b*64+t] = sigf(ivb[585+t]); wv[b*64+t] = ivb[649+t]; }
  if (t < 8) fr[b*8+t] = sigf(ivb[713+t]);
  if (t == 0) ag[b] = sigf(ivb[721]);
  if (t == 1) wg[b] = sigf(ivb[722]);
  if (t < 8){
    float m0 = ivb[723+t*3], m1 = ivb[723+t*3+1], m2 = ivb[723+t*3+2];
    float mx = fmaxf(m0, fmaxf(m1,m2));
    float e0 = expf(m0-mx), e1 = expf(m1-mx), e2 = expf(m2-mx);
    float inv = 1.f/(e0+e1+e2);
    md[(b*8+t)*3+0]=e0*inv; md[(b*8+t)*3+1]=e1*inv; md[(b*8+t)*3+2]=e2*inv;
  }
}

// ---------- allocation weights, sort-free; u computed inline ----------
__global__ __launch_bounds__(256) void k_alloc(const float* __restrict__ fr,
                                               const float* __restrict__ lrw,
                                               const float* __restrict__ lus,
                                               const float* __restrict__ lww,
                                               const float* __restrict__ nf,
                                               float* __restrict__ aw){
  __shared__ unsigned long long key[4096];
  __shared__ float lg[4096];
  __shared__ float part[64][5];
  int b = blockIdx.y;
  int i0 = blockIdx.x*64;
  int t = threadIdx.x;
  float frv[8];
  #pragma unroll
  for (int r=0;r<8;r++) frv[r] = fr[b*8+r];
  float nfv = nf[0];
  for (int idx=t; idx<4096; idx+=256){
    size_t bn = (size_t)b*ND + idx;
    float psi = 1.f;
    #pragma unroll
    for (int r=0;r<8;r++) psi *= 1.f - frv[r]*lrw[bn*8+r];
    float a = lus[bn], c = lww[bn];
    float uv = (a + c - a*c)*psi*nfv;
    unsigned int bits = __float_as_uint(uv);
    key[idx] = ((unsigned long long)bits << 32) | (unsigned int)idx;
    lg[idx] = logf(uv);
  }
  __syncthreads();
  int il = t & 63, c = t >> 6;
  unsigned long long ki = key[i0+il];
  float s = 0.f;
  int j0 = c*1024;
  #pragma unroll 4
  for (int j=j0; j<j0+1024; j++){
    s += (key[j] < ki) ? lg[j] : 0.f;
  }
  part[il][c] = s;
  __syncthreads();
  if (t < 64){
    float tot = part[t][0]+part[t][1]+part[t][2]+part[t][3];
    float uv = __uint_as_float((unsigned int)(key[i0+t] >> 32));
    aw[(size_t)b*ND + i0 + t] = (1.f - uv) * expf(tot);
  }
}

// ---------- write content: raw exp scores + global sum ----------
__global__ __launch_bounds__(256) void k_cw1(const float* __restrict__ memory,
                                             const float* __restrict__ wkn,
                                             const float* __restrict__ wb,
                                             float* __restrict__ cw, float* __restrict__ cws){
  int b = blockIdx.y, n0 = blockIdx.x*256, t = threadIdx.x;
  __shared__ float wk[64];
  __shared__ float tile[64][65];
  __shared__ float part[64][9];
  if (t < 64) wk[t] = wkn[b*64+t];
  float wbv = wb[b];
  float esum = 0.f;
  int row = t>>2, q4 = t&3;
  int n_l = t&63, q = t>>6;
  for (int sb=0; sb<4; sb++){
    const float* src = memory + ((size_t)b*ND + n0 + sb*64 + row)*64 + q4*16;
    float4 v0 = *(const float4*)(src+0);
    float4 v1 = *(const float4*)(src+4);
    float4 v2 = *(const float4*)(src+8);
    float4 v3 = *(const float4*)(src+12);
    float* d = &tile[row][q4*16];
    d[0]=v0.x; d[1]=v0.y; d[2]=v0.z; d[3]=v0.w;
    d[4]=v1.x; d[5]=v1.y; d[6]=v1.z; d[7]=v1.w;
    d[8]=v2.x; d[9]=v2.y; d[10]=v2.z; d[11]=v2.w;
    d[12]=v3.x; d[13]=v3.y; d[14]=v3.z; d[15]=v3.w;
    __syncthreads();
    float nr=0.f, dd=0.f;
    #pragma unroll
    for (int w=q*16; w<q*16+16; w++){
      float mv = tile[n_l][w];
      nr += mv*mv; dd += mv*wk[w];
    }
    part[n_l][q] = nr; part[n_l][4+q] = dd;
    __syncthreads();
    if (t < 64){
      float nrt = part[t][0]+part[t][1]+part[t][2]+part[t][3];
      float dt  = part[t][4]+part[t][5]+part[t][6]+part[t][7];
      float e = expf(wbv * dt/(sqrtf(nrt)+EPSF));
      cw[(size_t)b*ND + n0 + sb*64 + t] = e;
      esum += e;
    }
    __syncthreads();
  }
  if (t < 64){
    for (int o=32;o>0;o>>=1) esum += __shfl_xor(esum, o, 64);
    if (t == 0) atomicAdd(&cws[b], esum);
  }
}

// ---------- ww + wrw + Sp/Sw + new memory, fused ----------
__global__ __launch_bounds__(256) void k_wwmem(const float* __restrict__ aw, const float* __restrict__ cw,
                      const float* __restrict__ cws,
                      const float* __restrict__ ag, const float* __restrict__ wg,
                      const float* __restrict__ prec, const float* __restrict__ lrw,
                      const float* __restrict__ mem, const float* __restrict__ er,
                      const float* __restrict__ wvv,
                      float* __restrict__ ww, float* __restrict__ wrw,
                      float* __restrict__ Sp, float* __restrict__ Sw,
                      float* __restrict__ nm){
  int b = blockIdx.y;
  int n0 = blockIdx.x*256;
  int n = n0 + threadIdx.x;
  int t = threadIdx.x;
  __shared__ float ssp[8], ssw[8];
  __shared__ float wvs[256];
  __shared__ float er_s[64], wv_s[64];
  if (t<8){ ssp[t]=0.f; ssw[t]=0.f; }
  if (t<64){ er_s[t]=er[b*64+t]; wv_s[t]=wvv[b*64+t]; }
  __syncthreads();
  size_t bn = (size_t)b*ND + n;
  float agv = ag[b];
  float invc = 1.f/cws[b];
  float wv = wg[b]*(agv*aw[bn] + (1.f-agv)*cw[bn]*invc);
  ww[bn] = wv;
  wvs[t] = wv;
  float pv = prec[bn];
  #pragma unroll
  for (int r=0;r<8;r++){
    float rr = lrw[bn*8+r];
    float wr = wv*rr;
    wrw[bn*8+r] = wr;
    atomicAdd(&ssp[r], pv*rr);
    atomicAdd(&ssw[r], wr);
  }
  __syncthreads();
  if (t<8){ atomicAdd(&Sp[b*8+t], ssp[t]); atomicAdd(&Sw[b*8+t], ssw[t]); }
  // memory update for this n-range
  size_t base = ((size_t)b*ND + n0)*64;
  for (int idx=t; idx<256*64; idx+=256){
    int n_l = idx>>6, w = idx&63;
    float wwv = wvs[n_l];
    nm[base+idx] = mem[base+idx]*(1.f - wwv*er_s[w]) + wwv*wv_s[w];
  }
}

// ---------- fused fw (row pass) + bw (col pass) over tml ----------
#define TF(c,r,cc_) tileu[(c)*2112 + (r)*65 + (cc_)]
#define TB(c,r,cc_) tileu[(c)*2112 + (r)*33 + (cc_)]
__global__ __launch_bounds__(256) void k_fwbw(const float* __restrict__ tml,
    const float* __restrict__ rw, const float* __restrict__ wrw,
    const float* __restrict__ ww, const float* __restrict__ prec,
    const float* __restrict__ Sp, const float* __restrict__ Sw,
    const float* __restrict__ nf_p,
    float* __restrict__ fwv, float* __restrict__ bwv){
  __shared__ float tileu[2*2112];
  __shared__ float rwt[2][64][8];
  __shared__ float wrt[2][64][8];
  __shared__ float sred[256][33];
  int t = threadIdx.x;
  int isbw = blockIdx.x >= 128;
  int i0 = (blockIdx.x & 127)*32;
  int b = blockIdx.y;
  const float* tb = tml + (size_t)b*ND*ND;
  int ljj = t >> 3, lr = t & 7;
  float A[4][8], B[4][8];
  #pragma unroll
  for (int k=0;k<4;k++)
    #pragma unroll
    for (int r=0;r<8;r++){ A[k][r]=0.f; B[k][r]=0.f; }
  {
    rwt[0][ljj][lr]    = rw[((size_t)b*ND + ljj)*RDIM + lr];
    rwt[0][ljj+32][lr] = rw[((size_t)b*ND + ljj+32)*RDIM + lr];
    wrt[0][ljj][lr]    = wrw[((size_t)b*ND + ljj)*RDIM + lr];
    wrt[0][ljj+32][lr] = wrw[((size_t)b*ND + ljj+32)*RDIM + lr];
  }
  if (!isbw){
    int rg = t & 7, jg = t >> 3;
    int lrow = t >> 4, lc4 = t & 15;
    {
      const float4 v0 = *(const float4*)(tb + (size_t)(i0+lrow)*ND + lc4*4);
      const float4 v1 = *(const float4*)(tb + (size_t)(i0+lrow+16)*ND + lc4*4);
      TF(0,lrow,lc4*4+0)=v0.x; TF(0,lrow,lc4*4+1)=v0.y;
      TF(0,lrow,lc4*4+2)=v0.z; TF(0,lrow,lc4*4+3)=v0.w;
      TF(0,lrow+16,lc4*4+0)=v1.x; TF(0,lrow+16,lc4*4+1)=v1.y;
      TF(0,lrow+16,lc4*4+2)=v1.z; TF(0,lrow+16,lc4*4+3)=v1.w;
    }
    __syncthreads();
    float4 p0, p1; float prw0, prw1, pww0, pww1;
    for (int jt=0; jt<64; jt++){
      int cur = jt & 1;
      if (jt < 63){
        int j0 = (jt+1)*64;
        p0 = *(const float4*)(tb + (size_t)(i0+lrow)*ND + j0 + lc4*4);
        p1 = *(const float4*)(tb + (size_t)(i0+lrow+16)*ND + j0 + lc4*4);
        prw0 = rw[((size_t)b*ND + j0+ljj)*RDIM + lr];
        prw1 = rw[((size_t)b*ND + j0+ljj+32)*RDIM + lr];
        pww0 = wrw[((size_t)b*ND + j0+ljj)*RDIM + lr];
        pww1 = wrw[((size_t)b*ND + j0+ljj+32)*RDIM + lr];
      }
      #pragma unroll
      for (int jj=0;jj<2;jj++){
        int j = jg*2 + jj;
        float t0 = TF(cur,rg,j);
        float t1 = TF(cur,rg+8,j);
        float t2 = TF(cur,rg+16,j);
        float t3 = TF(cur,rg+24,j);
        const float4 ra = *(const float4*)&rwt[cur][j][0];
        const float4 rb4 = *(const float4*)&rwt[cur][j][4];
        const float4 wa = *(const float4*)&wrt[cur][j][0];
        const float4 wb4 = *(const float4*)&wrt[cur][j][4];
        float rv8[8] = {ra.x,ra.y,ra.z,ra.w,rb4.x,rb4.y,rb4.z,rb4.w};
        float wv8[8] = {wa.x,wa.y,wa.z,wa.w,wb4.x,wb4.y,wb4.z,wb4.w};
        #pragma unroll
        for (int r=0;r<8;r++){
          A[0][r] += t0*rv8[r]; A[1][r] += t1*rv8[r]; A[2][r] += t2*rv8[r]; A[3][r] += t3*rv8[r];
          B[0][r] += t0*wv8[r]; B[1][r] += t1*wv8[r]; B[2][r] += t2*wv8[r]; B[3][r] += t3*wv8[r];
        }
      }
      __syncthreads();
      if (jt < 63){
        int nb = cur ^ 1;
        TF(nb,lrow,lc4*4+0)=p0.x; TF(nb,lrow,lc4*4+1)=p0.y;
        TF(nb,lrow,lc4*4+2)=p0.z; TF(nb,lrow,lc4*4+3)=p0.w;
        TF(nb,lrow+16,lc4*4+0)=p1.x; TF(nb,lrow+16,lc4*4+1)=p1.y;
        TF(nb,lrow+16,lc4*4+2)=p1.z; TF(nb,lrow+16,lc4*4+3)=p1.w;
        rwt[nb][ljj][lr]=prw0; rwt[nb][ljj+32][lr]=prw1;
        wrt[nb][ljj][lr]=pww0; wrt[nb][ljj+32][lr]=pww1;
        __syncthreads();
      }
    }
  } else {
    int cg = t & 7, jg = t >> 3;
    int lrow = t >> 3, lc4 = t & 7;
    {
      const float4 v0 = *(const float4*)(tb + (size_t)(lrow)*ND + i0 + lc4*4);
      const float4 v1 = *(const float4*)(tb + (size_t)(lrow+32)*ND + i0 + lc4*4);
      TB(0,lrow,lc4*4+0)=v0.x; TB(0,lrow,lc4*4+1)=v0.y;
      TB(0,lrow,lc4*4+2)=v0.z; TB(0,lrow,lc4*4+3)=v0.w;
      TB(0,lrow+32,lc4*4+0)=v1.x; TB(0,lrow+32,lc4*4+1)=v1.y;
      TB(0,lrow+32,lc4*4+2)=v1.z; TB(0,lrow+32,lc4*4+3)=v1.w;
    }
    __syncthreads();
    float4 p0, p1; float prw0, prw1, pww0, pww1;
    for (int jt=0; jt<64; jt++){
      int cur = jt & 1;
      if (jt < 63){
        int j0 = (jt+1)*64;
        p0 = *(const float4*)(tb + (size_t)(j0+lrow)*ND + i0 + lc4*4);
        p1 = *(const float4*)(tb + (size_t)(j0+lrow+32)*ND + i0 + lc4*4);
        prw0 = rw[((size_t)b*ND + j0+ljj)*RDIM + lr];
        prw1 = rw[((size_t)b*ND + j0+ljj+32)*RDIM + lr];
        pww0 = wrw[((size_t)b*ND + j0+ljj)*RDIM + lr];
        pww1 = wrw[((size_t)b*ND + j0+ljj+32)*RDIM + lr];
      }
      #pragma unroll
      for (int jj=0;jj<2;jj++){
        int j = jg*2 + jj;
        float t0 = TB(cur,j,cg);
        float t1 = TB(cur,j,cg+8);
        float t2 = TB(cur,j,cg+16);
        float t3 = TB(cur,j,cg+24);
        const float4 ra = *(const float4*)&rwt[cur][j][0];
        const float4 rb4 = *(const float4*)&rwt[cur][j][4];
        const float4 wa = *(const float4*)&wrt[cur][j][0];
        const float4 wb4 = *(const float4*)&wrt[cur][j][4];
        float rv8[8] = {ra.x,ra.y,ra.z,ra.w,rb4.x,rb4.y,rb4.z,rb4.w};
        float wv8[8] = {wa.x,wa.y,wa.z,wa.w,wb4.x,wb4.y,wb4.z,wb4.w};
        #pragma unroll
        for (int r=0;r<8;r++){
          A[0][r] += t0*rv8[r]; A[1][r] += t1*rv8[r]; A[2][r] += t2*rv8[r]; A[3][r] += t3*rv8[r];
          B[0][r] += t0*wv8[r]; B[1][r] += t1*wv8[r]; B[2][r] += t2*wv8[r]; B[3][r] += t3*wv8[r];
        }
      }
      __syncthreads();
      if (jt < 63){
        int nb = cur ^ 1;
        TB(nb,lrow,lc4*4+0)=p0.x; TB(nb,lrow,lc4*4+1)=p0.y;
        TB(nb,lrow,lc4*4+2)=p0.z; TB(nb,lrow,lc4*4+3)=p0.w;
        TB(nb,lrow+32,lc4*4+0)=p1.x; TB(nb,lrow+32,lc4*4+1)=p1.y;
        TB(nb,lrow+32,lc4*4+2)=p1.z; TB(nb,lrow+32,lc4*4+3)=p1.w;
        rwt[nb][ljj][lr]=prw0; rwt[nb][ljj+32][lr]=prw1;
        wrt[nb][ljj][lr]=pww0; wrt[nb][ljj+32][lr]=pww1;
        __syncthreads();
      }
    }
  }
  // two-phase cross-thread reduction
  #pragma unroll
  for (int k=0;k<4;k++)
    #pragma unroll
    for (int r=0;r<8;r++) sred[t][k*8+r] = A[k][r];
  __syncthreads();
  float Af[8];
  int ig2 = t & 7, k2 = t >> 3;
  if (t < 32){
    #pragma unroll
    for (int r=0;r<8;r++) Af[r]=0.f;
    for (int g=0; g<32; g++){
      const float* s = sred[g*8 + ig2];
      #pragma unroll
      for (int r=0;r<8;r++) Af[r] += s[k2*8 + r];
    }
  }
  __syncthreads();
  #pragma unroll
  for (int k=0;k<4;k++)
    #pragma unroll
    for (int r=0;r<8;r++) sred[t][k*8+r] = B[k][r];
  __syncthreads();
  if (t < 32){
    float Bf[8];
    #pragma unroll
    for (int r=0;r<8;r++) Bf[r]=0.f;
    for (int g=0; g<32; g++){
      const float* s = sred[g*8 + ig2];
      #pragma unroll
      for (int r=0;r<8;r++) Bf[r] += s[k2*8 + r];
    }
    int i = i0 + ig2 + 8*k2;
    size_t bn = (size_t)b*ND + i;
    float wwi = ww[bn], pi = prec[bn];
    float tii = tb[(size_t)i*ND + i];
    float nfv = nf_p[0];
    if (!isbw){
      #pragma unroll
      for (int r=0;r<8;r++){
        float rwi = rw[bn*RDIM + r];
        float v = (1.f-wwi)*(Af[r] - tii*rwi) - (Bf[r] - tii*wwi*rwi)
                + wwi*(Sp[b*RDIM+r] - pi*rwi);
        fwv[bn*RDIM + r] = nfv * v;
      }
    } else {
      #pragma unroll
      for (int r=0;r<8;r++){
        float rwi = rw[bn*RDIM + r];
        float v = (1.f-wwi)*(Af[r] - tii*rwi) - (Bf[r] - tii*wwi*rwi)
                + pi*(Sw[b*RDIM+r] - wwi*rwi);
        bwv[bn*RDIM + r] = nfv * v;
      }
    }
  }
}

// ---------- read content + read-vector partial sums (rv fused) ----------
__global__ __launch_bounds__(256) void k_rcsrv(const float* __restrict__ nm,
                                               const float* __restrict__ rkn,
                                               const float* __restrict__ rb,
                                               const float* __restrict__ fwv,
                                               const float* __restrict__ bwv,
                                               const float* __restrict__ md,
                                               float* __restrict__ rss,
                                               float* __restrict__ rvc,
                                               float* __restrict__ rvd){
  int b = blockIdx.y, n0 = blockIdx.x*256, t = threadIdx.x;
  __shared__ float rk[8][64];
  __shared__ float tile[64][65];
  __shared__ float part[64][37];
  __shared__ float evs[64][9];
  __shared__ float evd[64][9];
  __shared__ float md_s[24];
  __shared__ float red[256][17];
  for (int p=0;p<2;p++){ int idx=t+p*256; rk[idx>>6][idx&63] = rkn[b*512 + idx]; }
  if (t < 24) md_s[t] = md[b*24 + t];
  float rbv[8];
  #pragma unroll
  for (int r=0;r<8;r++) rbv[r] = rb[b*8+r];
  float es[8], accC[8], accD[8];
  #pragma unroll
  for (int r=0;r<8;r++){ es[r]=0.f; accC[r]=0.f; accD[r]=0.f; }
  int row = t>>2, q4 = t&3;
  int n_l = t&63, q = t>>6;
  int wq = t & 63, g = t >> 6;
  __syncthreads();
  for (int sb=0; sb<4; sb++){
    const float* src = nm + ((size_t)b*ND + n0 + sb*64 + row)*64 + q4*16;
    float4 v0 = *(const float4*)(src+0);
    float4 v1 = *(const float4*)(src+4);
    float4 v2 = *(const float4*)(src+8);
    float4 v3 = *(const float4*)(src+12);
    float* d = &tile[row][q4*16];
    d[0]=v0.x; d[1]=v0.y; d[2]=v0.z; d[3]=v0.w;
    d[4]=v1.x; d[5]=v1.y; d[6]=v1.z; d[7]=v1.w;
    d[8]=v2.x; d[9]=v2.y; d[10]=v2.z; d[11]=v2.w;
    d[12]=v3.x; d[13]=v3.y; d[14]=v3.z; d[15]=v3.w;
    // directional mix loads (independent of tile)
    for (int p=0;p<2;p++){
      int idx = t + p*256;
      int nn = idx>>3, r = idx&7;
      size_t base = ((size_t)b*ND + n0 + sb*64 + nn)*8 + r;
      evd[nn][r] = md_s[r*3+0]*bwv[base] + md_s[r*3+2]*fwv[base];
    }
    __syncthreads();
    float nr=0.f, dd[8];
    #pragma unroll
    for (int r=0;r<8;r++) dd[r]=0.f;
    #pragma unroll
    for (int w=q*16; w<q*16+16; w++){
      float mv = tile[n_l][w];
      nr += mv*mv;
      #pragma unroll
      for (int r=0;r<8;r++) dd[r] += mv*rk[r][w];
    }
    part[n_l][q*9] = nr;
    #pragma unroll
    for (int r=0;r<8;r++) part[n_l][q*9+1+r] = dd[r];
    __syncthreads();
    if (t < 64){
      float nrt = part[t][0]+part[t][9]+part[t][18]+part[t][27];
      float inv = 1.f/(sqrtf(nrt)+EPSF);
      #pragma unroll
      for (int r=0;r<8;r++){
        float dt = part[t][1+r]+part[t][10+r]+part[t][19+r]+part[t][28+r];
        float e = expf(rbv[r]*dt*inv);
        evs[t][r] = e;
        es[r] += e;
      }
    }
    __syncthreads();
    // rv partial accumulation: thread (wq, g) covers n in [g*16, g*16+16)
    #pragma unroll 4
    for (int nn=g*16; nn<g*16+16; nn++){
      float mv = tile[nn][wq];
      #pragma unroll
      for (int r=0;r<8;r++){
        accC[r] += mv*evs[nn][r];
        accD[r] += mv*evd[nn][r];
      }
    }
    __syncthreads();
  }
  if (t < 64){
    #pragma unroll
    for (int r=0;r<8;r++){
      float v = es[r];
      for (int o=32;o>0;o>>=1) v += __shfl_xor(v, o, 64);
      if (t == 0) atomicAdd(&rss[b*8+r], v);
    }
  }
  #pragma unroll
  for (int r=0;r<8;r++){ red[t][r] = accC[r]; red[t][8+r] = accD[r]; }
  __syncthreads();
  if (t < 64){
    float sc[8], sd[8];
    #pragma unroll
    for (int r=0;r<8;r++){ sc[r]=0.f; sd[r]=0.f; }
    #pragma unroll
    for (int gg=0; gg<4; gg++){
      #pragma unroll
      for (int r=0;r<8;r++){
        sc[r] += red[gg*64+t][r];
        sd[r] += red[gg*64+t][8+r];
      }
    }
    #pragma unroll
    for (int r=0;r<8;r++){
      atomicAdd(&rvc[(b*64+t)*8+r], sc[r]);
      atomicAdd(&rvd[(b*64+t)*8+r], sd[r]);
    }
  }
}

// ---------- final: rv = rvd + (m1/rss)*rvc ; out += rv @ W_r ----------
__global__ void k_wr(const float* __restrict__ rvc, const float* __restrict__ rvd,
                     const float* __restrict__ rss, const float* __restrict__ md,
                     const float* __restrict__ W_r, float* __restrict__ out){
  int vc = blockIdx.x, kc = blockIdx.y;  // 16 x 4
  int t = threadIdx.x;
  int v = vc*256 + t;
  __shared__ float s[4][128];
  for (int idx=t; idx<512; idx+=256){
    int b=idx>>7, kk=idx&127;
    int k = kc*128+kk;
    int r = k & 7;
    float m1 = md[(b*8+r)*3+1];
    s[b][kk] = rvd[b*512+k] + m1*rvc[b*512+k]/rss[b*8+r];
  }
  __syncthreads();
  float a0=0,a1=0,a2=0,a3=0;
  for (int kk=0;kk<128;kk++){
    float w = W_r[(size_t)(kc*128+kk)*VTD + v];
    a0 += s[0][kk]*w; a1 += s[1][kk]*w; a2 += s[2][kk]*w; a3 += s[3][kk]*w;
  }
  atomicAdd(&out[0*VTD+v], a0); atomicAdd(&out[1*VTD+v], a1);
  atomicAdd(&out[2*VTD+v], a2); atomicAdd(&out[3*VTD+v], a3);
}

extern "C" void kernel_launch(void* const* d_in, const int* in_sizes, int n_in,
                              void* d_out, int out_size, void* d_ws, size_t ws_size,
                              hipStream_t stream) {
  const float* x_in  = (const float*)d_in[0];
  const float* prec  = (const float*)d_in[1];
  const float* tml   = (const float*)d_in[2];
  const float* memory= (const float*)d_in[3];
  const float* lrw   = (const float*)d_in[4];
  const float* lus   = (const float*)d_in[5];
  const float* lww   = (const float*)d_in[6];
  const float* nf    = (const float*)d_in[7];
  const float* lrv   = (const float*)d_in[8];
  const float* ch    = (const float*)d_in[9];
  const float* cc    = (const float*)d_in[10];
  const float* Wi    = (const float*)d_in[11];
  const float* Wf    = (const float*)d_in[12];
  const float* Wo    = (const float*)d_in[13];
  const float* Wsg   = (const float*)d_in[14];
  const float* b_i   = (const float*)d_in[15];
  const float* b_f   = (const float*)d_in[16];
  const float* b_o   = (const float*)d_in[17];
  const float* b_s   = (const float*)d_in[18];
  const float* W_y   = (const float*)d_in[19];
  const float* W_E   = (const float*)d_in[20];
  const float* W_r   = (const float*)d_in[21];
  float* ws = (float*)d_ws;
  float* out = (float*)d_out;

  hipMemsetAsync(ws, 0, (size_t)ZERO_FLOATS*sizeof(float), stream);
  hipMemsetAsync(out, 0, (size_t)out_size*sizeof(float), stream);

  // controller
  k_pre<<<dim3(7,16),256,0,stream>>>(x_in, lrv, ch, Wi, Wf, Wo, Wsg, ws+OFF_PRE);
  for (int l=1;l<LL;l++)
    k_glayer<<<dim3(2,4),256,0,stream>>>(ws+OFF_PRE, b_i,b_f,b_o,b_s, cc,
                                         Wi, Wf, Wo, Wsg, ws+OFF_FLAT, l);
  k_hfin<<<1,256,0,stream>>>(ws+OFF_PRE, b_i,b_f,b_o,b_s, cc, ws+OFF_FLAT);
  // projections (merged)
  k_proj<<<dim3(19,8),256,0,stream>>>(ws+OFF_FLAT, W_y, W_E, out, ws+OFF_IV);
  k_iface<<<4,256,0,stream>>>(ws+OFF_IV, ws+OFF_WKN, ws+OFF_RKN, ws+OFF_RB, ws+OFF_WB,
                              ws+OFF_ER, ws+OFF_WV, ws+OFF_FR, ws+OFF_AG, ws+OFF_WG, ws+OFF_MD);
  // allocation (u inline) + content write weights
  k_alloc<<<dim3(64,4),256,0,stream>>>(ws+OFF_FR, lrw, lus, lww, nf, ws+OFF_AW);
  k_cw1<<<dim3(16,4),256,0,stream>>>(memory, ws+OFF_WKN, ws+OFF_WB, ws+OFF_CW, ws+OFF_CWS);
  k_wwmem<<<dim3(16,4),256,0,stream>>>(ws+OFF_AW, ws+OFF_CW, ws+OFF_CWS, ws+OFF_AG, ws+OFF_WG,
                                       prec, lrw, memory, ws+OFF_ER, ws+OFF_WV,
                                       ws+OFF_WW, ws+OFF_WRW, ws+OFF_SP, ws+OFF_SW, ws+OFF_NM);
  // temporal link contractions, single launch
  k_fwbw<<<dim3(256,4),256,0,stream>>>(tml, lrw, ws+OFF_WRW, ws+OFF_WW, prec,
                                       ws+OFF_SP, ws+OFF_SW, nf, ws+OFF_FWD, ws+OFF_BWD);
  // read addressing + rv partials (fused) + readout
  k_rcsrv<<<dim3(16,4),256,0,stream>>>(ws+OFF_NM, ws+OFF_RKN, ws+OFF_RB,
                                       ws+OFF_FWD, ws+OFF_BWD, ws+OFF_MD,
                                       ws+OFF_RSS, ws+OFF_RVC, ws+OFF_RVD);
  k_wr<<<dim3(16,4),256,0,stream>>>(ws+OFF_RVC, ws+OFF_RVD, ws+OFF_RSS, ws+OFF_MD, W_r, out);
}

// Round 4
// 687.978 us; speedup vs baseline: 1.2667x; 1.0183x over previous
//
#include <hip/hip_runtime.h>

#define BSZ 4
#define XD 1024
#define HD 256
#define LL 4
#define VTD 4096
#define WDIM 64
#define RDIM 8
#define ND 4096
#define ETD 747
#define IND 2048
#define EPSF 1e-8f

// ---- workspace layout (float offsets) ----
// zeroed (atomic targets):
#define OFF_PRE 0            // [L][4][BS][H] = 16384
#define OFF_IV 16384         // [BS][747] = 2988
#define OFF_SP 19372         // [BS][8]
#define OFF_SW 19404         // [BS][8]
#define OFF_RVD 19436        // [BS][64][8]
#define OFF_RVC 21484        // [BS][64][8]
#define OFF_CWS 23532        // [BS]
#define OFF_RSS 23536        // [BS][8]
#define ZERO_FLOATS 23568
// not zeroed:
#define OFF_FLAT 23568       // [BS][1024] (layers 0..2 used)
#define OFF_WKN 27664        // [BS][64]   (written by iface block, unused downstream)
#define OFF_RKN 27920        // [BS][8][64]
#define OFF_RB 29968         // [BS][8]
#define OFF_WB 30000         // [BS]
#define OFF_ER 30004         // [BS][64]
#define OFF_WV 30260         // [BS][64]
#define OFF_FR 30516         // [BS][8]
#define OFF_AG 30548         // [BS]
#define OFF_WG 30552         // [BS]
#define OFF_MD 30556         // [BS][8][3]
#define OFF_AW 30652         // [BS][N]
#define OFF_CW 47036         // [BS][N] raw exp
#define OFF_WW 63420         // [BS][N]
#define OFF_WRW 79804        // [BS][N][8]
#define OFF_NM 210876        // [BS][N][64]
#define OFF_FWD 1259452      // [BS][N][8]
#define OFF_BWD 1390524      // [BS][N][8]

__device__ __forceinline__ float sigf(float x){ return 1.f/(1.f+expf(-x)); }
__device__ __forceinline__ float splus(float z){ return fmaxf(z,0.f) + log1pf(expf(-fabsf(z))); }

// ---------- LSTM: known-input part of all gates, all layers ----------
__global__ void k_pre(const float* __restrict__ x_in, const float* __restrict__ lrv,
                      const float* __restrict__ ch,
                      const float* __restrict__ Wi, const float* __restrict__ Wf,
                      const float* __restrict__ Wo, const float* __restrict__ Wsg,
                      float* __restrict__ pre){
  int kc = blockIdx.x;          // 0..13 (14 chunks of 128 over k<1792)
  int lg = blockIdx.y;          // 0..15
  int l = lg >> 2, g = lg & 3;
  int t = threadIdx.x;
  __shared__ float s[4][128];
  for (int idx = t; idx < 512; idx += 256){
    int b = idx >> 7, kk = idx & 127;
    int k = kc*128 + kk;
    float v;
    if (k < 1024)      v = x_in[b*XD + k];
    else if (k < 1536) v = lrv[b*512 + (k-1024)];
    else               v = ch[(b*LL + l)*HD + (k-1536)];
    s[b][kk] = v;
  }
  __syncthreads();
  const float* Wg = (g==0?Wi:g==1?Wf:g==2?Wo:Wsg) + (size_t)l*IND*HD;
  float a0=0,a1=0,a2=0,a3=0;
  for (int kk=0; kk<128; kk++){
    float w = Wg[(size_t)(kc*128+kk)*HD + t];
    a0 += s[0][kk]*w; a1 += s[1][kk]*w; a2 += s[2][kk]*w; a3 += s[3][kk]*w;
  }
  float* p = pre + (size_t)((l*4+g)*4)*HD + t;
  atomicAdd(p + 0*HD, a0); atomicAdd(p + 1*HD, a1);
  atomicAdd(p + 2*HD, a2); atomicAdd(p + 3*HD, a3);
}

// ---------- fused: h_{l-1} from pre, add W.h_{l-1} into pre[l] ----------
__global__ void k_glayer(float* __restrict__ pre,
                         const float* __restrict__ b_i, const float* __restrict__ b_f,
                         const float* __restrict__ b_o, const float* __restrict__ b_s,
                         const float* __restrict__ cc,
                         const float* __restrict__ Wi, const float* __restrict__ Wf,
                         const float* __restrict__ Wo, const float* __restrict__ Wsg,
                         float* __restrict__ flat, int l){
  int t = threadIdx.x;
  int lm = l - 1;
  __shared__ float hs[4][257];
  float bi = b_i[lm*HD+t], bf = b_f[lm*HD+t], bo = b_o[lm*HD+t], bs = b_s[lm*HD+t];
  for (int b=0;b<BSZ;b++){
    float pi = pre[((lm*4+0)*4+b)*HD+t];
    float pf = pre[((lm*4+1)*4+b)*HD+t];
    float po = pre[((lm*4+2)*4+b)*HD+t];
    float ps = pre[((lm*4+3)*4+b)*HD+t];
    float ig = sigf(pi+bi), fg = sigf(pf+bf), og = sigf(po+bo);
    float sg = tanhf(ps+bs);
    float c = fg*cc[(b*LL+lm)*HD+t] + ig*sg;
    float h = og*tanhf(c);
    hs[b][t] = h;
    flat[b*1024 + lm*HD + t] = h;
  }
  __syncthreads();
  int kc = blockIdx.x;          // 0..1
  int g  = blockIdx.y;          // 0..3
  const float* Wg = (g==0?Wi:g==1?Wf:g==2?Wo:Wsg) + (size_t)l*IND*HD;
  float a0=0,a1=0,a2=0,a3=0;
  for (int kk=0; kk<128; kk++){
    int k = kc*128 + kk;
    float w = Wg[(size_t)(1792 + k)*HD + t];
    a0 += hs[0][k]*w; a1 += hs[1][k]*w; a2 += hs[2][k]*w; a3 += hs[3][k]*w;
  }
  float* p = pre + (size_t)((l*4+g)*4)*HD + t;
  atomicAdd(p + 0*HD, a0); atomicAdd(p + 1*HD, a1);
  atomicAdd(p + 2*HD, a2); atomicAdd(p + 3*HD, a3);
}

// ---------- projections (h3 computed inline from pre): y=flat@W_y, iv=flat@W_E ----------
__global__ void k_proj(const float* __restrict__ flat, const float* __restrict__ pre,
                       const float* __restrict__ b_i, const float* __restrict__ b_f,
                       const float* __restrict__ b_o, const float* __restrict__ b_s,
                       const float* __restrict__ cc,
                       const float* __restrict__ W_y, const float* __restrict__ W_E,
                       float* __restrict__ out, float* __restrict__ iv){
  int bx = blockIdx.x, kc = blockIdx.y;   // bx 0..18, kc 0..7
  int t = threadIdx.x;
  __shared__ float s[4][128];
  for (int idx=t; idx<512; idx+=256){
    int b=idx>>7, kk=idx&127;
    float v;
    if (kc < 6){
      v = flat[b*1024 + kc*128+kk];
    } else {
      int h = (kc-6)*128 + kk;      // layer-3 hidden
      float pi = pre[((12+0)*4+b)*HD+h];
      float pf = pre[((12+1)*4+b)*HD+h];
      float po = pre[((12+2)*4+b)*HD+h];
      float ps = pre[((12+3)*4+b)*HD+h];
      float ig = sigf(pi+b_i[768+h]), fg = sigf(pf+b_f[768+h]), og = sigf(po+b_o[768+h]);
      float sg = tanhf(ps+b_s[768+h]);
      float c = fg*cc[(b*LL+3)*HD+h] + ig*sg;
      v = og*tanhf(c);
    }
    s[b][kk] = v;
  }
  __syncthreads();
  float a0=0,a1=0,a2=0,a3=0;
  if (bx < 16){
    int v = bx*256 + t;
    for (int kk=0;kk<128;kk++){
      float w = W_y[(size_t)(kc*128+kk)*VTD + v];
      a0 += s[0][kk]*w; a1 += s[1][kk]*w; a2 += s[2][kk]*w; a3 += s[3][kk]*w;
    }
    atomicAdd(&out[0*VTD+v], a0); atomicAdd(&out[1*VTD+v], a1);
    atomicAdd(&out[2*VTD+v], a2); atomicAdd(&out[3*VTD+v], a3);
  } else {
    int v = (bx-16)*256 + t;
    if (v >= ETD) return;
    for (int kk=0;kk<128;kk++){
      float w = W_E[(size_t)(kc*128+kk)*ETD + v];
      a0 += s[0][kk]*w; a1 += s[1][kk]*w; a2 += s[2][kk]*w; a3 += s[3][kk]*w;
    }
    atomicAdd(&iv[0*ETD+v], a0); atomicAdd(&iv[1*ETD+v], a1);
    atomicAdd(&iv[2*ETD+v], a2); atomicAdd(&iv[3*ETD+v], a3);
  }
}

// ---------- merged: alloc (bx<64) + write-content (bx 64..79) + iface (bx==80) ----------
union AddrSmem {
  struct { unsigned long long key[4096]; float lg[4096]; float part[64][5]; } a;
  struct { float wk[64]; float tile[64][65]; float part[64][9]; } c;
};

__global__ __launch_bounds__(256) void k_addr(const float* __restrict__ iv,
    const float* __restrict__ lrw, const float* __restrict__ lus,
    const float* __restrict__ lww, const float* __restrict__ nf,
    const float* __restrict__ memory,
    float* __restrict__ aw, float* __restrict__ cw, float* __restrict__ cws,
    float* wkn, float* rkn, float* rb, float* wb, float* er, float* wv,
    float* fr, float* ag, float* wg, float* md){
  __shared__ AddrSmem sm;
  __shared__ float rk2[8];
  int bx = blockIdx.x;
  int b = blockIdx.y;
  int t = threadIdx.x;
  const float* ivb = iv + b*ETD;

  if (bx < 64){
    // ---- allocation weights (sort-free log-domain rank product); u inline ----
    float frv[8];
    #pragma unroll
    for (int r=0;r<8;r++) frv[r] = sigf(ivb[713+r]);
    float nfv = nf[0];
    int i0 = bx*64;
    for (int idx=t; idx<4096; idx+=256){
      size_t bn = (size_t)b*ND + idx;
      float psi = 1.f;
      #pragma unroll
      for (int r=0;r<8;r++) psi *= 1.f - frv[r]*lrw[bn*8+r];
      float a = lus[bn], c = lww[bn];
      float uv = (a + c - a*c)*psi*nfv;
      unsigned int bits = __float_as_uint(uv);
      sm.a.key[idx] = ((unsigned long long)bits << 32) | (unsigned int)idx;
      sm.a.lg[idx] = logf(uv);
    }
    __syncthreads();
    int il = t & 63, c = t >> 6;
    unsigned long long ki = sm.a.key[i0+il];
    float s = 0.f;
    int j0 = c*1024;
    #pragma unroll 4
    for (int j=j0; j<j0+1024; j++){
      s += (sm.a.key[j] < ki) ? sm.a.lg[j] : 0.f;
    }
    sm.a.part[il][c] = s;
    __syncthreads();
    if (t < 64){
      float tot = sm.a.part[t][0]+sm.a.part[t][1]+sm.a.part[t][2]+sm.a.part[t][3];
      float uv = __uint_as_float((unsigned int)(sm.a.key[i0+t] >> 32));
      aw[(size_t)b*ND + i0 + t] = (1.f - uv) * expf(tot);
    }
  } else if (bx < 80){
    // ---- write content weights: raw exp + global sum ----
    int n0 = (bx-64)*256;
    // compute normalized write key locally
    float wkv = 0.f, ss = 0.f;
    if (t < 64){ wkv = ivb[520 + t]; ss = wkv*wkv; }
    for (int o=32;o>0;o>>=1) ss += __shfl_xor(ss, o, 64);
    if (t < 64) sm.c.wk[t] = wkv/(sqrtf(ss)+EPSF);
    float wbv = 1.f + splus(-ivb[584]);
    __syncthreads();
    float esum = 0.f;
    int row = t>>2, q4 = t&3;
    int n_l = t&63, q = t>>6;
    for (int sb=0; sb<4; sb++){
      const float* src = memory + ((size_t)b*ND + n0 + sb*64 + row)*64 + q4*16;
      float4 v0 = *(const float4*)(src+0);
      float4 v1 = *(const float4*)(src+4);
      float4 v2 = *(const float4*)(src+8);
      float4 v3 = *(const float4*)(src+12);
      float* d = &sm.c.tile[row][q4*16];
      d[0]=v0.x; d[1]=v0.y; d[2]=v0.z; d[3]=v0.w;
      d[4]=v1.x; d[5]=v1.y; d[6]=v1.z; d[7]=v1.w;
      d[8]=v2.x; d[9]=v2.y; d[10]=v2.z; d[11]=v2.w;
      d[12]=v3.x; d[13]=v3.y; d[14]=v3.z; d[15]=v3.w;
      __syncthreads();
      float nr=0.f, dd=0.f;
      #pragma unroll
      for (int w=q*16; w<q*16+16; w++){
        float mv = sm.c.tile[n_l][w];
        nr += mv*mv; dd += mv*sm.c.wk[w];
      }
      sm.c.part[n_l][q] = nr; sm.c.part[n_l][4+q] = dd;
      __syncthreads();
      if (t < 64){
        float nrt = sm.c.part[t][0]+sm.c.part[t][1]+sm.c.part[t][2]+sm.c.part[t][3];
        float dt  = sm.c.part[t][4]+sm.c.part[t][5]+sm.c.part[t][6]+sm.c.part[t][7];
        float e = expf(wbv * dt/(sqrtf(nrt)+EPSF));
        cw[(size_t)b*ND + n0 + sb*64 + t] = e;
        esum += e;
      }
      __syncthreads();
    }
    if (t < 64){
      for (int o=32;o>0;o>>=1) esum += __shfl_xor(esum, o, 64);
      if (t == 0) atomicAdd(&cws[b], esum);
    }
  } else {
    // ---- interface post-processing (outputs for later stages) ----
    if (t < 8) rk2[t] = 0.f;
    __syncthreads();
    for (int p=0;p<2;p++){
      int idx = t + p*256; int w = idx>>3, r = idx&7;
      float v = ivb[w*8 + r];
      atomicAdd(&rk2[r], v*v);
    }
    float wkv = 0.f, ss = 0.f;
    if (t < 64){ wkv = ivb[520 + t]; ss = wkv*wkv; }
    for (int o=32;o>0;o>>=1) ss += __shfl_xor(ss, o, 64);
    if (t < 64) wkn[b*64 + t] = wkv/(sqrtf(ss)+EPSF);
    __syncthreads();
    for (int p=0;p<2;p++){
      int idx = t + p*256; int w = idx>>3, r = idx&7;
      float v = ivb[w*8 + r];
      rkn[b*512 + r*64 + w] = v/(sqrtf(rk2[r])+EPSF);
    }
    if (t < 8) rb[b*8+t] = 1.f + splus(-ivb[512+t]);
    if (t == 0) wb[b] = 1.f + splus(-ivb[584]);
    if (t < 64){ er[b*64+t] = sigf(ivb[585+t]); wv[b*64+t] = ivb[649+t]; }
    if (t < 8) fr[b*8+t] = sigf(ivb[713+t]);
    if (t == 0) ag[b] = sigf(ivb[721]);
    if (t == 1) wg[b] = sigf(ivb[722]);
    if (t < 8){
      float m0 = ivb[723+t*3], m1 = ivb[723+t*3+1], m2 = ivb[723+t*3+2];
      float mx = fmaxf(m0, fmaxf(m1,m2));
      float e0 = expf(m0-mx), e1 = expf(m1-mx), e2 = expf(m2-mx);
      float inv = 1.f/(e0+e1+e2);
      md[(b*8+t)*3+0]=e0*inv; md[(b*8+t)*3+1]=e1*inv; md[(b*8+t)*3+2]=e2*inv;
    }
  }
}

// ---------- ww + wrw + Sp/Sw + new memory, fused ----------
__global__ __launch_bounds__(256) void k_wwmem(const float* __restrict__ aw, const float* __restrict__ cw,
                      const float* __restrict__ cws,
                      const float* __restrict__ ag, const float* __restrict__ wg,
                      const float* __restrict__ prec, const float* __restrict__ lrw,
                      const float* __restrict__ mem, const float* __restrict__ er,
                      const float* __restrict__ wvv,
                      float* __restrict__ ww, float* __restrict__ wrw,
                      float* __restrict__ Sp, float* __restrict__ Sw,
                      float* __restrict__ nm){
  int b = blockIdx.y;
  int n0 = blockIdx.x*256;
  int n = n0 + threadIdx.x;
  int t = threadIdx.x;
  __shared__ float ssp[8], ssw[8];
  __shared__ float wvs[256];
  __shared__ float er_s[64], wv_s[64];
  if (t<8){ ssp[t]=0.f; ssw[t]=0.f; }
  if (t<64){ er_s[t]=er[b*64+t]; wv_s[t]=wvv[b*64+t]; }
  __syncthreads();
  size_t bn = (size_t)b*ND + n;
  float agv = ag[b];
  float invc = 1.f/cws[b];
  float wv = wg[b]*(agv*aw[bn] + (1.f-agv)*cw[bn]*invc);
  ww[bn] = wv;
  wvs[t] = wv;
  float pv = prec[bn];
  #pragma unroll
  for (int r=0;r<8;r++){
    float rr = lrw[bn*8+r];
    float wr = wv*rr;
    wrw[bn*8+r] = wr;
    atomicAdd(&ssp[r], pv*rr);
    atomicAdd(&ssw[r], wr);
  }
  __syncthreads();
  if (t<8){ atomicAdd(&Sp[b*8+t], ssp[t]); atomicAdd(&Sw[b*8+t], ssw[t]); }
  size_t base = ((size_t)b*ND + n0)*64;
  for (int idx=t; idx<256*64; idx+=256){
    int n_l = idx>>6, w = idx&63;
    float wwv = wvs[n_l];
    nm[base+idx] = mem[base+idx]*(1.f - wwv*er_s[w]) + wwv*wv_s[w];
  }
}

// ---------- fused fw (row pass) + bw (col pass) over tml ----------
// single barrier per j-tile; in-wave shuffle reduction (no 33KB sred)
#define TF(c,r,cc_) tileu[(c)*2112 + (r)*65 + (cc_)]
#define TB(c,r,cc_) tileu[(c)*2112 + (r)*33 + (cc_)]
__global__ __launch_bounds__(256) void k_fwbw(const float* __restrict__ tml,
    const float* __restrict__ rw, const float* __restrict__ wrw,
    const float* __restrict__ ww, const float* __restrict__ prec,
    const float* __restrict__ Sp, const float* __restrict__ Sw,
    const float* __restrict__ nf_p,
    float* __restrict__ fwv, float* __restrict__ bwv){
  __shared__ float tileu[2*2112];
  __shared__ float rwt[2][64][8];
  __shared__ float wrt[2][64][8];
  __shared__ float swA[4][8][32];
  __shared__ float swB[4][8][32];
  int t = threadIdx.x;
  int lane = t & 63, wav = t >> 6;
  int isbw = blockIdx.x >= 128;
  int i0 = (blockIdx.x & 127)*32;
  int b = blockIdx.y;
  const float* tb = tml + (size_t)b*ND*ND;
  int ljj = t >> 3, lr = t & 7;
  int rg = t & 7, jg = t >> 3;
  float A[4][8], B[4][8];
  #pragma unroll
  for (int k=0;k<4;k++)
    #pragma unroll
    for (int r=0;r<8;r++){ A[k][r]=0.f; B[k][r]=0.f; }
  // initial staging (buffer 0)
  rwt[0][ljj][lr]    = rw[((size_t)b*ND + ljj)*RDIM + lr];
  rwt[0][ljj+32][lr] = rw[((size_t)b*ND + ljj+32)*RDIM + lr];
  wrt[0][ljj][lr]    = wrw[((size_t)b*ND + ljj)*RDIM + lr];
  wrt[0][ljj+32][lr] = wrw[((size_t)b*ND + ljj+32)*RDIM + lr];
  if (!isbw){
    int lrow = t >> 4, lc4 = t & 15;
    const float4 v0 = *(const float4*)(tb + (size_t)(i0+lrow)*ND + lc4*4);
    const float4 v1 = *(const float4*)(tb + (size_t)(i0+lrow+16)*ND + lc4*4);
    TF(0,lrow,lc4*4+0)=v0.x; TF(0,lrow,lc4*4+1)=v0.y;
    TF(0,lrow,lc4*4+2)=v0.z; TF(0,lrow,lc4*4+3)=v0.w;
    TF(0,lrow+16,lc4*4+0)=v1.x; TF(0,lrow+16,lc4*4+1)=v1.y;
    TF(0,lrow+16,lc4*4+2)=v1.z; TF(0,lrow+16,lc4*4+3)=v1.w;
  } else {
    int lrow = t >> 3, lc4 = t & 7;
    const float4 v0 = *(const float4*)(tb + (size_t)(lrow)*ND + i0 + lc4*4);
    const float4 v1 = *(const float4*)(tb + (size_t)(lrow+32)*ND + i0 + lc4*4);
    TB(0,lrow,lc4*4+0)=v0.x; TB(0,lrow,lc4*4+1)=v0.y;
    TB(0,lrow,lc4*4+2)=v0.z; TB(0,lrow,lc4*4+3)=v0.w;
    TB(0,lrow+32,lc4*4+0)=v1.x; TB(0,lrow+32,lc4*4+1)=v1.y;
    TB(0,lrow+32,lc4*4+2)=v1.z; TB(0,lrow+32,lc4*4+3)=v1.w;
  }
  __syncthreads();
  float4 p0, p1; float prw0, prw1, pww0, pww1;
  for (int jt=0; jt<64; jt++){
    int cur = jt & 1;
    if (jt < 63){
      int j0 = (jt+1)*64;
      if (!isbw){
        int lrow = t >> 4, lc4 = t & 15;
        p0 = *(const float4*)(tb + (size_t)(i0+lrow)*ND + j0 + lc4*4);
        p1 = *(const float4*)(tb + (size_t)(i0+lrow+16)*ND + j0 + lc4*4);
      } else {
        int lrow = t >> 3, lc4 = t & 7;
        p0 = *(const float4*)(tb + (size_t)(j0+lrow)*ND + i0 + lc4*4);
        p1 = *(const float4*)(tb + (size_t)(j0+lrow+32)*ND + i0 + lc4*4);
      }
      prw0 = rw[((size_t)b*ND + j0+ljj)*RDIM + lr];
      prw1 = rw[((size_t)b*ND + j0+ljj+32)*RDIM + lr];
      pww0 = wrw[((size_t)b*ND + j0+ljj)*RDIM + lr];
      pww1 = wrw[((size_t)b*ND + j0+ljj+32)*RDIM + lr];
    }
    #pragma unroll
    for (int jj=0;jj<2;jj++){
      int j = jg*2 + jj;
      float t0,t1,t2,t3;
      if (!isbw){
        t0 = TF(cur,rg,j); t1 = TF(cur,rg+8,j);
        t2 = TF(cur,rg+16,j); t3 = TF(cur,rg+24,j);
      } else {
        t0 = TB(cur,j,rg); t1 = TB(cur,j,rg+8);
        t2 = TB(cur,j,rg+16); t3 = TB(cur,j,rg+24);
      }
      const float4 ra = *(const float4*)&rwt[cur][j][0];
      const float4 rb4 = *(const float4*)&rwt[cur][j][4];
      const float4 wa = *(const float4*)&wrt[cur][j][0];
      const float4 wb4 = *(const float4*)&wrt[cur][j][4];
      float rv8[8] = {ra.x,ra.y,ra.z,ra.w,rb4.x,rb4.y,rb4.z,rb4.w};
      float wv8[8] = {wa.x,wa.y,wa.z,wa.w,wb4.x,wb4.y,wb4.z,wb4.w};
      #pragma unroll
      for (int r=0;r<8;r++){
        A[0][r] += t0*rv8[r]; A[1][r] += t1*rv8[r]; A[2][r] += t2*rv8[r]; A[3][r] += t3*rv8[r];
        B[0][r] += t0*wv8[r]; B[1][r] += t1*wv8[r]; B[2][r] += t2*wv8[r]; B[3][r] += t3*wv8[r];
      }
    }
    if (jt < 63){
      int nb = cur ^ 1;
      if (!isbw){
        int lrow = t >> 4, lc4 = t & 15;
        TF(nb,lrow,lc4*4+0)=p0.x; TF(nb,lrow,lc4*4+1)=p0.y;
        TF(nb,lrow,lc4*4+2)=p0.z; TF(nb,lrow,lc4*4+3)=p0.w;
        TF(nb,lrow+16,lc4*4+0)=p1.x; TF(nb,lrow+16,lc4*4+1)=p1.y;
        TF(nb,lrow+16,lc4*4+2)=p1.z; TF(nb,lrow+16,lc4*4+3)=p1.w;
      } else {
        int lrow = t >> 3, lc4 = t & 7;
        TB(nb,lrow,lc4*4+0)=p0.x; TB(nb,lrow,lc4*4+1)=p0.y;
        TB(nb,lrow,lc4*4+2)=p0.z; TB(nb,lrow,lc4*4+3)=p0.w;
        TB(nb,lrow+32,lc4*4+0)=p1.x; TB(nb,lrow+32,lc4*4+1)=p1.y;
        TB(nb,lrow+32,lc4*4+2)=p1.z; TB(nb,lrow+32,lc4*4+3)=p1.w;
      }
      rwt[nb][ljj][lr]=prw0; rwt[nb][ljj+32][lr]=prw1;
      wrt[nb][ljj][lr]=pww0; wrt[nb][ljj+32][lr]=pww1;
    }
    __syncthreads();   // single barrier per j-tile (write(nb) vs read(nb)@jt+1)
  }
  // in-wave reduce over jg (lane bits 3,4,5), lanes sharing t&7 hold same rows
  #pragma unroll
  for (int k=0;k<4;k++)
    #pragma unroll
    for (int r=0;r<8;r++){
      float va = A[k][r];
      va += __shfl_xor(va, 8, 64);
      va += __shfl_xor(va, 16, 64);
      va += __shfl_xor(va, 32, 64);
      A[k][r] = va;
      float vb = B[k][r];
      vb += __shfl_xor(vb, 8, 64);
      vb += __shfl_xor(vb, 16, 64);
      vb += __shfl_xor(vb, 32, 64);
      B[k][r] = vb;
    }
  if (lane < 8){
    #pragma unroll
    for (int k=0;k<4;k++)
      #pragma unroll
      for (int r=0;r<8;r++){
        swA[wav][lane][k*8+r] = A[k][r];
        swB[wav][lane][k*8+r] = B[k][r];
      }
  }
  __syncthreads();
  if (t < 32){
    int ig2 = t & 7, k2 = t >> 3;
    float Af[8], Bf[8];
    #pragma unroll
    for (int r=0;r<8;r++){
      Af[r] = swA[0][ig2][k2*8+r] + swA[1][ig2][k2*8+r]
            + swA[2][ig2][k2*8+r] + swA[3][ig2][k2*8+r];
      Bf[r] = swB[0][ig2][k2*8+r] + swB[1][ig2][k2*8+r]
            + swB[2][ig2][k2*8+r] + swB[3][ig2][k2*8+r];
    }
    int i = i0 + ig2 + 8*k2;
    size_t bn = (size_t)b*ND + i;
    float wwi = ww[bn], pi = prec[bn];
    float tii = tb[(size_t)i*ND + i];
    float nfv = nf_p[0];
    if (!isbw){
      #pragma unroll
      for (int r=0;r<8;r++){
        float rwi = rw[bn*RDIM + r];
        float v = (1.f-wwi)*(Af[r] - tii*rwi) - (Bf[r] - tii*wwi*rwi)
                + wwi*(Sp[b*RDIM+r] - pi*rwi);
        fwv[bn*RDIM + r] = nfv * v;
      }
    } else {
      #pragma unroll
      for (int r=0;r<8;r++){
        float rwi = rw[bn*RDIM + r];
        float v = (1.f-wwi)*(Af[r] - tii*rwi) - (Bf[r] - tii*wwi*rwi)
                + pi*(Sw[b*RDIM+r] - wwi*rwi);
        bwv[bn*RDIM + r] = nfv * v;
      }
    }
  }
}

// ---------- read content + read-vector partial sums (rv fused) ----------
__global__ __launch_bounds__(256) void k_rcsrv(const float* __restrict__ nm,
                                               const float* __restrict__ rkn,
                                               const float* __restrict__ rb,
                                               const float* __restrict__ fwv,
                                               const float* __restrict__ bwv,
                                               const float* __restrict__ md,
                                               float* __restrict__ rss,
                                               float* __restrict__ rvc,
                                               float* __restrict__ rvd){
  int b = blockIdx.y, n0 = blockIdx.x*256, t = threadIdx.x;
  __shared__ float rk[8][64];
  __shared__ float tile[64][65];
  __shared__ float part[64][37];
  __shared__ float evs[64][9];
  __shared__ float evd[64][9];
  __shared__ float md_s[24];
  __shared__ float red[256][17];
  for (int p=0;p<2;p++){ int idx=t+p*256; rk[idx>>6][idx&63] = rkn[b*512 + idx]; }
  if (t < 24) md_s[t] = md[b*24 + t];
  float rbv[8];
  #pragma unroll
  for (int r=0;r<8;r++) rbv[r] = rb[b*8+r];
  float es[8], accC[8], accD[8];
  #pragma unroll
  for (int r=0;r<8;r++){ es[r]=0.f; accC[r]=0.f; accD[r]=0.f; }
  int row = t>>2, q4 = t&3;
  int n_l = t&63, q = t>>6;
  int wq = t & 63, g = t >> 6;
  __syncthreads();
  for (int sb=0; sb<4; sb++){
    const float* src = nm + ((size_t)b*ND + n0 + sb*64 + row)*64 + q4*16;
    float4 v0 = *(const float4*)(src+0);
    float4 v1 = *(const float4*)(src+4);
    float4 v2 = *(const float4*)(src+8);
    float4 v3 = *(const float4*)(src+12);
    float* d = &tile[row][q4*16];
    d[0]=v0.x; d[1]=v0.y; d[2]=v0.z; d[3]=v0.w;
    d[4]=v1.x; d[5]=v1.y; d[6]=v1.z; d[7]=v1.w;
    d[8]=v2.x; d[9]=v2.y; d[10]=v2.z; d[11]=v2.w;
    d[12]=v3.x; d[13]=v3.y; d[14]=v3.z; d[15]=v3.w;
    for (int p=0;p<2;p++){
      int idx = t + p*256;
      int nn = idx>>3, r = idx&7;
      size_t base = ((size_t)b*ND + n0 + sb*64 + nn)*8 + r;
      evd[nn][r] = md_s[r*3+0]*bwv[base] + md_s[r*3+2]*fwv[base];
    }
    __syncthreads();
    float nr=0.f, dd[8];
    #pragma unroll
    for (int r=0;r<8;r++) dd[r]=0.f;
    #pragma unroll
    for (int w=q*16; w<q*16+16; w++){
      float mv = tile[n_l][w];
      nr += mv*mv;
      #pragma unroll
      for (int r=0;r<8;r++) dd[r] += mv*rk[r][w];
    }
    part[n_l][q*9] = nr;
    #pragma unroll
    for (int r=0;r<8;r++) part[n_l][q*9+1+r] = dd[r];
    __syncthreads();
    if (t < 64){
      float nrt = part[t][0]+part[t][9]+part[t][18]+part[t][27];
      float inv = 1.f/(sqrtf(nrt)+EPSF);
      #pragma unroll
      for (int r=0;r<8;r++){
        float dt = part[t][1+r]+part[t][10+r]+part[t][19+r]+part[t][28+r];
        float e = expf(rbv[r]*dt*inv);
        evs[t][r] = e;
        es[r] += e;
      }
    }
    __syncthreads();
    #pragma unroll 4
    for (int nn=g*16; nn<g*16+16; nn++){
      float mv = tile[nn][wq];
      #pragma unroll
      for (int r=0;r<8;r++){
        accC[r] += mv*evs[nn][r];
        accD[r] += mv*evd[nn][r];
      }
    }
    __syncthreads();
  }
  if (t < 64){
    #pragma unroll
    for (int r=0;r<8;r++){
      float v = es[r];
      for (int o=32;o>0;o>>=1) v += __shfl_xor(v, o, 64);
      if (t == 0) atomicAdd(&rss[b*8+r], v);
    }
  }
  #pragma unroll
  for (int r=0;r<8;r++){ red[t][r] = accC[r]; red[t][8+r] = accD[r]; }
  __syncthreads();
  if (t < 64){
    float sc[8], sd[8];
    #pragma unroll
    for (int r=0;r<8;r++){ sc[r]=0.f; sd[r]=0.f; }
    #pragma unroll
    for (int gg=0; gg<4; gg++){
      #pragma unroll
      for (int r=0;r<8;r++){
        sc[r] += red[gg*64+t][r];
        sd[r] += red[gg*64+t][8+r];
      }
    }
    #pragma unroll
    for (int r=0;r<8;r++){
      atomicAdd(&rvc[(b*64+t)*8+r], sc[r]);
      atomicAdd(&rvd[(b*64+t)*8+r], sd[r]);
    }
  }
}

// ---------- final: rv = rvd + (m1/rss)*rvc ; out += rv @ W_r ----------
__global__ void k_wr(const float* __restrict__ rvc, const float* __restrict__ rvd,
                     const float* __restrict__ rss, const float* __restrict__ md,
                     const float* __restrict__ W_r, float* __restrict__ out){
  int vc = blockIdx.x, kc = blockIdx.y;  // 16 x 4
  int t = threadIdx.x;
  int v = vc*256 + t;
  __shared__ float s[4][128];
  for (int idx=t; idx<512; idx+=256){
    int b=idx>>7, kk=idx&127;
    int k = kc*128+kk;
    int r = k & 7;
    float m1 = md[(b*8+r)*3+1];
    s[b][kk] = rvd[b*512+k] + m1*rvc[b*512+k]/rss[b*8+r];
  }
  __syncthreads();
  float a0=0,a1=0,a2=0,a3=0;
  for (int kk=0;kk<128;kk++){
    float w = W_r[(size_t)(kc*128+kk)*VTD + v];
    a0 += s[0][kk]*w; a1 += s[1][kk]*w; a2 += s[2][kk]*w; a3 += s[3][kk]*w;
  }
  atomicAdd(&out[0*VTD+v], a0); atomicAdd(&out[1*VTD+v], a1);
  atomicAdd(&out[2*VTD+v], a2); atomicAdd(&out[3*VTD+v], a3);
}

extern "C" void kernel_launch(void* const* d_in, const int* in_sizes, int n_in,
                              void* d_out, int out_size, void* d_ws, size_t ws_size,
                              hipStream_t stream) {
  const float* x_in  = (const float*)d_in[0];
  const float* prec  = (const float*)d_in[1];
  const float* tml   = (const float*)d_in[2];
  const float* memory= (const float*)d_in[3];
  const float* lrw   = (const float*)d_in[4];
  const float* lus   = (const float*)d_in[5];
  const float* lww   = (const float*)d_in[6];
  const float* nf    = (const float*)d_in[7];
  const float* lrv   = (const float*)d_in[8];
  const float* ch    = (const float*)d_in[9];
  const float* cc    = (const float*)d_in[10];
  const float* Wi    = (const float*)d_in[11];
  const float* Wf    = (const float*)d_in[12];
  const float* Wo    = (const float*)d_in[13];
  const float* Wsg   = (const float*)d_in[14];
  const float* b_i   = (const float*)d_in[15];
  const float* b_f   = (const float*)d_in[16];
  const float* b_o   = (const float*)d_in[17];
  const float* b_s   = (const float*)d_in[18];
  const float* W_y   = (const float*)d_in[19];
  const float* W_E   = (const float*)d_in[20];
  const float* W_r   = (const float*)d_in[21];
  float* ws = (float*)d_ws;
  float* out = (float*)d_out;

  hipMemsetAsync(ws, 0, (size_t)ZERO_FLOATS*sizeof(float), stream);
  hipMemsetAsync(out, 0, (size_t)out_size*sizeof(float), stream);

  // controller
  k_pre<<<dim3(14,16),256,0,stream>>>(x_in, lrv, ch, Wi, Wf, Wo, Wsg, ws+OFF_PRE);
  for (int l=1;l<LL;l++)
    k_glayer<<<dim3(2,4),256,0,stream>>>(ws+OFF_PRE, b_i,b_f,b_o,b_s, cc,
                                         Wi, Wf, Wo, Wsg, ws+OFF_FLAT, l);
  // projections (h3 inline)
  k_proj<<<dim3(19,8),256,0,stream>>>(ws+OFF_FLAT, ws+OFF_PRE, b_i,b_f,b_o,b_s, cc,
                                      W_y, W_E, out, ws+OFF_IV);
  // alloc + write-content + iface, one dispatch
  k_addr<<<dim3(81,4),256,0,stream>>>(ws+OFF_IV, lrw, lus, lww, nf, memory,
                                      ws+OFF_AW, ws+OFF_CW, ws+OFF_CWS,
                                      ws+OFF_WKN, ws+OFF_RKN, ws+OFF_RB, ws+OFF_WB,
                                      ws+OFF_ER, ws+OFF_WV, ws+OFF_FR, ws+OFF_AG,
                                      ws+OFF_WG, ws+OFF_MD);
  k_wwmem<<<dim3(16,4),256,0,stream>>>(ws+OFF_AW, ws+OFF_CW, ws+OFF_CWS, ws+OFF_AG, ws+OFF_WG,
                                       prec, lrw, memory, ws+OFF_ER, ws+OFF_WV,
                                       ws+OFF_WW, ws+OFF_WRW, ws+OFF_SP, ws+OFF_SW, ws+OFF_NM);
  // temporal link contractions, single launch
  k_fwbw<<<dim3(256,4),256,0,stream>>>(tml, lrw, ws+OFF_WRW, ws+OFF_WW, prec,
                                       ws+OFF_SP, ws+OFF_SW, nf, ws+OFF_FWD, ws+OFF_BWD);
  // read addressing + rv partials (fused) + readout
  k_rcsrv<<<dim3(16,4),256,0,stream>>>(ws+OFF_NM, ws+OFF_RKN, ws+OFF_RB,
                                       ws+OFF_FWD, ws+OFF_BWD, ws+OFF_MD,
                                       ws+OFF_RSS, ws+OFF_RVC, ws+OFF_RVD);
  k_wr<<<dim3(16,4),256,0,stream>>>(ws+OFF_RVC, ws+OFF_RVD, ws+OFF_RSS, ws+OFF_MD, W_r, out);
}